// Round 2
// baseline (911.302 us; speedup 1.0000x reference)
//
#include <hip/hip_runtime.h>
#include <hip/hip_bf16.h>
#include <math.h>

#define N_NODES 50000
#define N_EDGES 800000
#define F_IN    128
#define ED_DIM  16
#define D1      64    /* H1*C1 */
#define NGRAPH  256
#define OUT_C   128

// ---------------------------------------------------------------- histogram
__global__ void hist_kernel(const int* __restrict__ dst, int* __restrict__ deg) {
  int i = blockIdx.x * blockDim.x + threadIdx.x;
  int stride = gridDim.x * blockDim.x;
  for (; i < N_EDGES; i += stride) atomicAdd(&deg[dst[i]], 1);
}

// ---------------------------------------------------------------- exclusive scan (single block, 1024 thr)
__global__ void scan_kernel(const int* __restrict__ deg, int* __restrict__ offs) {
  __shared__ int sh[1024];
  int t = threadIdx.x;
  int carry = 0;
  for (int base = 0; base < N_NODES; base += 1024) {
    int i = base + t;
    int v = (i < N_NODES) ? deg[i] : 0;
    sh[t] = v;
    __syncthreads();
    for (int o = 1; o < 1024; o <<= 1) {
      int tv = (t >= o) ? sh[t - o] : 0;
      __syncthreads();
      sh[t] += tv;
      __syncthreads();
    }
    int incl = sh[t];
    int tot = sh[1023];
    if (i < N_NODES) offs[i + 1] = carry + incl;
    carry += tot;
    __syncthreads();
  }
  if (t == 0) offs[0] = 0;
}

// ---------------------------------------------------------------- scatter edges to CSR + per-edge attention logits
__global__ void scatter_kernel(const int* __restrict__ src, const int* __restrict__ dst,
                               const float* __restrict__ ea,
                               const float* __restrict__ We1, const float* __restrict__ ae1,
                               const float* __restrict__ We2, const float* __restrict__ ae2,
                               const int* __restrict__ offs, int* __restrict__ cnt,
                               int* __restrict__ csr_src,
                               float* __restrict__ al_e1s, float* __restrict__ al_e2s) {
  __shared__ float M1s[16][8];
  __shared__ float M2s[16];
  int t = threadIdx.x;
  if (t < 128) {
    int d = t >> 3, h = t & 7;
    float s = 0.f;
    #pragma unroll
    for (int c = 0; c < 8; ++c) s = fmaf(We1[d * 64 + h * 8 + c], ae1[h * 8 + c], s);
    M1s[d][h] = s;
  } else if (t < 144) {
    int d = t - 128;
    float s = 0.f;
    for (int c = 0; c < 128; ++c) s = fmaf(We2[d * 128 + c], ae2[c], s);
    M2s[d] = s;
  }
  __syncthreads();
  int i = blockIdx.x * blockDim.x + t;
  int stride = gridDim.x * blockDim.x;
  for (; i < N_EDGES; i += stride) {
    int s = src[i], d = dst[i];
    float e[16];
    const float4* ea4 = (const float4*)(ea + (size_t)i * 16);
    #pragma unroll
    for (int q = 0; q < 4; ++q) {
      float4 v = ea4[q];
      e[q * 4] = v.x; e[q * 4 + 1] = v.y; e[q * 4 + 2] = v.z; e[q * 4 + 3] = v.w;
    }
    int pos = offs[d] + atomicAdd(&cnt[d], 1);
    csr_src[pos] = s;
    float r[8];
    #pragma unroll
    for (int h = 0; h < 8; ++h) {
      float sacc = 0.f;
      #pragma unroll
      for (int dd = 0; dd < 16; ++dd) sacc = fmaf(e[dd], M1s[dd][h], sacc);
      r[h] = sacc;
    }
    float4* o4 = (float4*)(al_e1s + (size_t)pos * 8);
    o4[0] = make_float4(r[0], r[1], r[2], r[3]);
    o4[1] = make_float4(r[4], r[5], r[6], r[7]);
    float s2 = 0.f;
    #pragma unroll
    for (int dd = 0; dd < 16; ++dd) s2 = fmaf(e[dd], M2s[dd], s2);
    al_e2s[pos] = s2;
  }
}

// ---------------------------------------------------------------- xw1 = x @ W1  (+ al_s1, al_d1)
__global__ void gemm1_kernel(const float* __restrict__ x, const float* __restrict__ W1,
                             const float* __restrict__ as1, const float* __restrict__ ad1,
                             float* __restrict__ xw1, float* __restrict__ al_s1,
                             float* __restrict__ al_d1) {
  __shared__ float Wl[F_IN * D1];
  int t = threadIdx.x;
  for (int i = t; i < F_IN * D1; i += 256) Wl[i] = W1[i];
  __syncthreads();
  int lane = t & 63, w = t >> 6;
  float asv = as1[lane], adv = ad1[lane];
  int waveId = blockIdx.x * 4 + w;
  int nw = gridDim.x * 4;
  for (int row = waveId; row < N_NODES; row += nw) {
    float x0 = x[(size_t)row * F_IN + lane];
    float x1 = x[(size_t)row * F_IN + 64 + lane];
    float acc = 0.f;
    #pragma unroll
    for (int k = 0; k < 64; ++k) {
      float xv = __shfl(x0, k);
      acc = fmaf(xv, Wl[k * 64 + lane], acc);
    }
    #pragma unroll
    for (int k = 0; k < 64; ++k) {
      float xv = __shfl(x1, k);
      acc = fmaf(xv, Wl[(64 + k) * 64 + lane], acc);
    }
    xw1[(size_t)row * 64 + lane] = acc;
    float ps = acc * asv, pd = acc * adv;
    ps += __shfl_xor(ps, 1); pd += __shfl_xor(pd, 1);
    ps += __shfl_xor(ps, 2); pd += __shfl_xor(pd, 2);
    ps += __shfl_xor(ps, 4); pd += __shfl_xor(pd, 4);
    if ((lane & 7) == 0) {
      al_s1[row * 8 + (lane >> 3)] = ps;
      al_d1[row * 8 + (lane >> 3)] = pd;
    }
  }
}

// ---------------------------------------------------------------- layer-1 aggregate (online softmax), wave per dst node
__global__ void agg1_kernel(const int* __restrict__ offs, const int* __restrict__ csr_src,
                            const float* __restrict__ al_s1, const float* __restrict__ al_d1,
                            const float* __restrict__ al_e1s, const float* __restrict__ xw1,
                            const float* __restrict__ b1, float* __restrict__ h1) {
  int node = blockIdx.x * 4 + (threadIdx.x >> 6);
  if (node >= N_NODES) return;
  int lane = threadIdx.x & 63;
  int h = lane >> 3;
  int base = offs[node], end = offs[node + 1];
  int degn = end - base;
  float adv = al_d1[node * 8 + h];
  float m = -INFINITY, ssum = 0.f, acc = 0.f, sume = 0.f;
  for (int j = base; j < end; ++j) {
    int sid = csr_src[j];
    float ae = al_e1s[(size_t)j * 8 + h];
    sume += ae;
    float a = al_s1[sid * 8 + h] + adv + ae;
    a = (a > 0.f) ? a : 0.2f * a;
    float nm = fmaxf(m, a);
    float sc = __expf(m - nm);
    float e = __expf(a - nm);
    ssum = ssum * sc + e;
    acc = acc * sc + e * xw1[(size_t)sid * 64 + lane];
    m = nm;
  }
  // self loop: al_e_self = mean of incoming al_e (linearity of ea @ M1)
  float aes = sume / (float)max(degn, 1);
  float a = al_s1[node * 8 + h] + adv + aes;
  a = (a > 0.f) ? a : 0.2f * a;
  float nm = fmaxf(m, a);
  float sc = __expf(m - nm);
  float e = __expf(a - nm);
  ssum = ssum * sc + e;
  acc = acc * sc + e * xw1[(size_t)node * 64 + lane];
  float o = acc / (ssum + 1e-16f) + b1[lane];
  h1[(size_t)node * 64 + lane] = (o > 0.f) ? o : expm1f(o);
}

// ---------------------------------------------------------------- xw2 = h1 @ W2  (+ al_s2, al_d2)
__global__ void gemm2_kernel(const float* __restrict__ h1, const float* __restrict__ W2,
                             const float* __restrict__ as2, const float* __restrict__ ad2,
                             float* __restrict__ xw2, float* __restrict__ al_s2,
                             float* __restrict__ al_d2) {
  __shared__ float Wl[D1 * OUT_C];
  int t = threadIdx.x;
  for (int i = t; i < D1 * OUT_C; i += 256) Wl[i] = W2[i];
  __syncthreads();
  int lane = t & 63, w = t >> 6;
  float as0 = as2[lane], as1v = as2[lane + 64];
  float ad0 = ad2[lane], ad1v = ad2[lane + 64];
  int waveId = blockIdx.x * 4 + w;
  int nw = gridDim.x * 4;
  for (int row = waveId; row < N_NODES; row += nw) {
    float hr = h1[(size_t)row * 64 + lane];
    float acc0 = 0.f, acc1 = 0.f;
    #pragma unroll
    for (int k = 0; k < 64; ++k) {
      float hv = __shfl(hr, k);
      acc0 = fmaf(hv, Wl[k * 128 + lane], acc0);
      acc1 = fmaf(hv, Wl[k * 128 + 64 + lane], acc1);
    }
    xw2[(size_t)row * 128 + lane] = acc0;
    xw2[(size_t)row * 128 + 64 + lane] = acc1;
    float ps = acc0 * as0 + acc1 * as1v;
    float pd = acc0 * ad0 + acc1 * ad1v;
    #pragma unroll
    for (int o = 1; o < 64; o <<= 1) {
      ps += __shfl_xor(ps, o);
      pd += __shfl_xor(pd, o);
    }
    if (lane == 0) { al_s2[row] = ps; al_d2[row] = pd; }
  }
}

// ---------------------------------------------------------------- layer-2 aggregate, wave per dst node (128 ch, 2/lane)
__global__ void agg2_kernel(const int* __restrict__ offs, const int* __restrict__ csr_src,
                            const float* __restrict__ al_s2, const float* __restrict__ al_d2,
                            const float* __restrict__ al_e2s, const float* __restrict__ xw2,
                            const float* __restrict__ b2, float* __restrict__ h2) {
  int node = blockIdx.x * 4 + (threadIdx.x >> 6);
  if (node >= N_NODES) return;
  int lane = threadIdx.x & 63;
  int base = offs[node], end = offs[node + 1];
  int degn = end - base;
  float adv = al_d2[node];
  float m = -INFINITY, ssum = 0.f, acc0 = 0.f, acc1 = 0.f, sume = 0.f;
  for (int j = base; j < end; ++j) {
    int sid = csr_src[j];
    float ae = al_e2s[j];
    sume += ae;
    float a = al_s2[sid] + adv + ae;
    a = (a > 0.f) ? a : 0.2f * a;
    float nm = fmaxf(m, a);
    float sc = __expf(m - nm);
    float e = __expf(a - nm);
    ssum = ssum * sc + e;
    acc0 = acc0 * sc + e * xw2[(size_t)sid * 128 + lane];
    acc1 = acc1 * sc + e * xw2[(size_t)sid * 128 + 64 + lane];
    m = nm;
  }
  float aes = sume / (float)max(degn, 1);
  float a = al_s2[node] + adv + aes;
  a = (a > 0.f) ? a : 0.2f * a;
  float nm = fmaxf(m, a);
  float sc = __expf(m - nm);
  float e = __expf(a - nm);
  ssum = ssum * sc + e;
  acc0 = acc0 * sc + e * xw2[(size_t)node * 128 + lane];
  acc1 = acc1 * sc + e * xw2[(size_t)node * 128 + 64 + lane];
  float inv = 1.f / (ssum + 1e-16f);
  h2[(size_t)node * 128 + lane] = acc0 * inv + b2[lane];
  h2[(size_t)node * 128 + 64 + lane] = acc1 * inv + b2[lane + 64];
}

// ---------------------------------------------------------------- graph boundaries (batch is sorted)
__global__ void gstart_kernel(const int* __restrict__ batch, int* __restrict__ gstart) {
  int n = blockIdx.x * blockDim.x + threadIdx.x;
  if (n >= N_NODES) return;
  int b = batch[n];
  if (n == 0) {
    for (int g = 0; g <= b; ++g) gstart[g] = 0;
  } else {
    int pb = batch[n - 1];
    for (int g = pb + 1; g <= b; ++g) gstart[g] = n;
  }
  if (n == N_NODES - 1) {
    for (int g = b + 1; g <= NGRAPH; ++g) gstart[g] = N_NODES;
  }
}

// ---------------------------------------------------------------- mean pool, block per graph
__global__ void pool_kernel(const float* __restrict__ h2, const int* __restrict__ gstart,
                            float* __restrict__ out) {
  int g = blockIdx.x;
  int c = threadIdx.x;  // 128
  int s0 = gstart[g], s1 = gstart[g + 1];
  float s = 0.f;
  for (int r = s0; r < s1; ++r) s += h2[(size_t)r * 128 + c];
  out[g * 128 + c] = s / fmaxf((float)(s1 - s0), 1.f);
}

// ================================================================ launch
extern "C" void kernel_launch(void* const* d_in, const int* in_sizes, int n_in,
                              void* d_out, int out_size, void* d_ws, size_t ws_size,
                              hipStream_t stream) {
  const float* x      = (const float*)d_in[0];
  const int*   eidx   = (const int*)d_in[1];
  const float* ea     = (const float*)d_in[2];
  const int*   batch  = (const int*)d_in[3];
  const float* W1     = (const float*)d_in[4];
  const float* as1    = (const float*)d_in[5];
  const float* ad1    = (const float*)d_in[6];
  const float* ae1    = (const float*)d_in[7];
  const float* We1    = (const float*)d_in[8];
  const float* b1     = (const float*)d_in[9];
  const float* W2     = (const float*)d_in[10];
  const float* as2    = (const float*)d_in[11];
  const float* ad2    = (const float*)d_in[12];
  const float* ae2    = (const float*)d_in[13];
  const float* We2    = (const float*)d_in[14];
  const float* b2     = (const float*)d_in[15];
  float* out = (float*)d_out;

  const int* src = eidx;
  const int* dst = eidx + N_EDGES;

  char* base = (char*)d_ws;
  size_t o = 0;
  #define ALLOC(name, bytes) size_t name = o; o += (((size_t)(bytes)) + 255) & ~(size_t)255;
  ALLOC(o_degcnt, 2 * N_NODES * 4)            // deg at [0,N), cnt at [N,2N)
  ALLOC(o_offs,   (N_NODES + 1) * 4)
  ALLOC(o_csr,    N_EDGES * 4)
  ALLOC(o_ale1,   (size_t)N_EDGES * 8 * 4)
  ALLOC(o_ale2,   N_EDGES * 4)
  ALLOC(o_xw1,    (size_t)N_NODES * 64 * 4)
  ALLOC(o_als1,   N_NODES * 8 * 4)
  ALLOC(o_ald1,   N_NODES * 8 * 4)
  ALLOC(o_h1,     (size_t)N_NODES * 64 * 4)
  ALLOC(o_xw2,    (size_t)N_NODES * 128 * 4)
  ALLOC(o_als2,   N_NODES * 4)
  ALLOC(o_ald2,   N_NODES * 4)
  ALLOC(o_h2,     (size_t)N_NODES * 128 * 4)
  ALLOC(o_gs,     (NGRAPH + 1) * 4)
  #undef ALLOC

  int*   deg     = (int*)(base + o_degcnt);
  int*   cnt     = deg + N_NODES;
  int*   offs    = (int*)(base + o_offs);
  int*   csr_src = (int*)(base + o_csr);
  float* al_e1s  = (float*)(base + o_ale1);
  float* al_e2s  = (float*)(base + o_ale2);
  float* xw1     = (float*)(base + o_xw1);
  float* al_s1   = (float*)(base + o_als1);
  float* al_d1   = (float*)(base + o_ald1);
  float* h1      = (float*)(base + o_h1);
  float* xw2     = (float*)(base + o_xw2);
  float* al_s2   = (float*)(base + o_als2);
  float* al_d2   = (float*)(base + o_ald2);
  float* h2      = (float*)(base + o_h2);
  int*   gstart  = (int*)(base + o_gs);

  hipMemsetAsync(deg, 0, (size_t)2 * N_NODES * 4, stream);

  hist_kernel<<<1024, 256, 0, stream>>>(dst, deg);
  scan_kernel<<<1, 1024, 0, stream>>>(deg, offs);
  scatter_kernel<<<2048, 256, 0, stream>>>(src, dst, ea, We1, ae1, We2, ae2,
                                           offs, cnt, csr_src, al_e1s, al_e2s);
  gemm1_kernel<<<1024, 256, 0, stream>>>(x, W1, as1, ad1, xw1, al_s1, al_d1);
  agg1_kernel<<<(N_NODES + 3) / 4, 256, 0, stream>>>(offs, csr_src, al_s1, al_d1,
                                                     al_e1s, xw1, b1, h1);
  gemm2_kernel<<<1024, 256, 0, stream>>>(h1, W2, as2, ad2, xw2, al_s2, al_d2);
  agg2_kernel<<<(N_NODES + 3) / 4, 256, 0, stream>>>(offs, csr_src, al_s2, al_d2,
                                                     al_e2s, xw2, b2, h2);
  gstart_kernel<<<(N_NODES + 255) / 256, 256, 0, stream>>>(batch, gstart);
  pool_kernel<<<NGRAPH, 128, 0, stream>>>(h2, gstart, out);
}

// Round 4
// 586.982 us; speedup vs baseline: 1.5525x; 1.5525x over previous
//
#include <hip/hip_runtime.h>
#include <hip/hip_bf16.h>
#include <math.h>

#define N_NODES 50000
#define N_EDGES 800000
#define F_IN    128
#define ED_DIM  16
#define D1      64    /* H1*C1 */
#define NGRAPH  256
#define OUT_C   128

// ---------------------------------------------------------------- prep: transpose W1->W1t[64][128], W2->W2t[128][64]
__global__ void prep_kernel(const float* __restrict__ W1, const float* __restrict__ W2,
                            float* __restrict__ W1t, float* __restrict__ W2t) {
  int t = blockIdx.x * 256 + threadIdx.x;
  if (t < 64 * 128) {
    int k = t >> 6, c = t & 63;          // W1[k*64+c], k<128
    W1t[c * 128 + k] = W1[t];
    int k2 = t >> 7, c2 = t & 127;       // W2[k*128+c], k<64
    W2t[c2 * 64 + k2] = W2[t];
  }
}

// ---------------------------------------------------------------- histogram
__global__ void hist_kernel(const int* __restrict__ dst, int* __restrict__ deg) {
  int i = blockIdx.x * blockDim.x + threadIdx.x;
  int stride = gridDim.x * blockDim.x;
  for (; i < N_EDGES; i += stride) atomicAdd(&deg[dst[i]], 1);
}

// ---------------------------------------------------------------- hierarchical scan (3 kernels)
__global__ void scan1_kernel(const int* __restrict__ deg, int* __restrict__ offs,
                             int* __restrict__ bsum) {
  __shared__ int sh[256];
  int b = blockIdx.x, t = threadIdx.x, i = b * 256 + t;
  int v = (i < N_NODES) ? deg[i] : 0;
  sh[t] = v;
  __syncthreads();
  for (int o = 1; o < 256; o <<= 1) {
    int tv = (t >= o) ? sh[t - o] : 0;
    __syncthreads();
    sh[t] += tv;
    __syncthreads();
  }
  if (i < N_NODES) offs[i + 1] = sh[t];
  if (t == 255) bsum[b] = sh[255];
}

__global__ void scan2_kernel(int* __restrict__ bsum) {  // 196 entries, 1 block
  __shared__ int sh[256];
  int t = threadIdx.x;
  sh[t] = (t < 196) ? bsum[t] : 0;
  __syncthreads();
  for (int o = 1; o < 256; o <<= 1) {
    int tv = (t >= o) ? sh[t - o] : 0;
    __syncthreads();
    sh[t] += tv;
    __syncthreads();
  }
  if (t < 196) bsum[t] = (t > 0) ? sh[t - 1] : 0;  // exclusive
}

__global__ void scan3_kernel(const int* __restrict__ bsum, int* __restrict__ offs) {
  int b = blockIdx.x, t = threadIdx.x, i = b * 256 + t;
  if (i < N_NODES) offs[i + 1] += bsum[b];
  if (i == 0) offs[0] = 0;
}

// ---------------------------------------------------------------- scatter edges to CSR + per-edge attention logits
__global__ void scatter_kernel(const int* __restrict__ src, const int* __restrict__ dst,
                               const float* __restrict__ ea,
                               const float* __restrict__ We1, const float* __restrict__ ae1,
                               const float* __restrict__ We2, const float* __restrict__ ae2,
                               const int* __restrict__ offs, int* __restrict__ cnt,
                               int* __restrict__ csr_src,
                               float* __restrict__ al_e1s, float* __restrict__ al_e2s) {
  __shared__ float M1s[16][8];
  __shared__ float M2s[16];
  int t = threadIdx.x;
  if (t < 128) {
    int d = t >> 3, h = t & 7;
    float s = 0.f;
    #pragma unroll
    for (int c = 0; c < 8; ++c) s = fmaf(We1[d * 64 + h * 8 + c], ae1[h * 8 + c], s);
    M1s[d][h] = s;
  } else if (t < 144) {
    int d = t - 128;
    float s = 0.f;
    for (int c = 0; c < 128; ++c) s = fmaf(We2[d * 128 + c], ae2[c], s);
    M2s[d] = s;
  }
  __syncthreads();
  int i = blockIdx.x * blockDim.x + t;
  int stride = gridDim.x * blockDim.x;
  for (; i < N_EDGES; i += stride) {
    int s = src[i], d = dst[i];
    float e[16];
    const float4* ea4 = (const float4*)(ea + (size_t)i * 16);
    #pragma unroll
    for (int q = 0; q < 4; ++q) {
      float4 v = ea4[q];
      e[q * 4] = v.x; e[q * 4 + 1] = v.y; e[q * 4 + 2] = v.z; e[q * 4 + 3] = v.w;
    }
    int pos = offs[d] + atomicAdd(&cnt[d], 1);
    csr_src[pos] = s;
    float r[8];
    #pragma unroll
    for (int h = 0; h < 8; ++h) {
      float sacc = 0.f;
      #pragma unroll
      for (int dd = 0; dd < 16; ++dd) sacc = fmaf(e[dd], M1s[dd][h], sacc);
      r[h] = sacc;
    }
    float4* o4 = (float4*)(al_e1s + (size_t)pos * 8);
    o4[0] = make_float4(r[0], r[1], r[2], r[3]);
    o4[1] = make_float4(r[4], r[5], r[6], r[7]);
    float s2 = 0.f;
    #pragma unroll
    for (int dd = 0; dd < 16; ++dd) s2 = fmaf(e[dd], M2s[dd], s2);
    al_e2s[pos] = s2;
  }
}

// ---------------------------------------------------------------- gemm1: xw1 = x @ W1 (tiled), fused al_s1/al_d1
// tile: 64 rows x 64 cols, K=128. thread: rows r4..r4+3 (r4=(t>>4)*4), cols c0+16j (c0=t&15).
__global__ __launch_bounds__(256) void gemm1_kernel(
    const float* __restrict__ x, const float* __restrict__ W1t,
    const float* __restrict__ as1, const float* __restrict__ ad1,
    float* __restrict__ xw1, float* __restrict__ al_s1, float* __restrict__ al_d1) {
  __shared__ float xl[64 * 132];   // 64 rows x (128 + 4 pad)
  __shared__ float wl[64 * 132];   // 64 cols x (128 + 4 pad)
  int t = threadIdx.x;
  int row0 = blockIdx.x * 64;
  const float4* xg = (const float4*)(x + (size_t)row0 * 128);
  const float4* wg = (const float4*)W1t;
  #pragma unroll
  for (int j = 0; j < 8; ++j) {
    int idx = t + j * 256;          // float4 index in 64x32 grid
    int r = idx >> 5, kq = idx & 31;
    float4 v = make_float4(0.f, 0.f, 0.f, 0.f);
    if (row0 + r < N_NODES) v = xg[r * 32 + kq];
    *(float4*)&xl[r * 132 + kq * 4] = v;
    *(float4*)&wl[(idx >> 5) * 132 + kq * 4] = wg[idx];
  }
  __syncthreads();
  int c0 = t & 15;
  int r4 = (t >> 4) * 4;
  float acc[4][4];
  #pragma unroll
  for (int i = 0; i < 4; ++i)
    #pragma unroll
    for (int j = 0; j < 4; ++j) acc[i][j] = 0.f;
  #pragma unroll 4
  for (int kq = 0; kq < 32; ++kq) {
    float4 xv[4], wv[4];
    #pragma unroll
    for (int i = 0; i < 4; ++i) xv[i] = *(const float4*)&xl[(r4 + i) * 132 + kq * 4];
    #pragma unroll
    for (int j = 0; j < 4; ++j) wv[j] = *(const float4*)&wl[(c0 + 16 * j) * 132 + kq * 4];
    #pragma unroll
    for (int i = 0; i < 4; ++i)
      #pragma unroll
      for (int j = 0; j < 4; ++j) {
        acc[i][j] = fmaf(xv[i].x, wv[j].x, acc[i][j]);
        acc[i][j] = fmaf(xv[i].y, wv[j].y, acc[i][j]);
        acc[i][j] = fmaf(xv[i].z, wv[j].z, acc[i][j]);
        acc[i][j] = fmaf(xv[i].w, wv[j].w, acc[i][j]);
      }
  }
  // store xw1
  #pragma unroll
  for (int i = 0; i < 4; ++i) {
    int r = row0 + r4 + i;
    if (r < N_NODES) {
      #pragma unroll
      for (int j = 0; j < 4; ++j) xw1[(size_t)r * 64 + c0 + 16 * j] = acc[i][j];
    }
  }
  // fused al_s1/al_d1: head h = 2j + (c0>>3); reduce over c0&7
  float ps[4][4], pd[4][4];
  #pragma unroll
  for (int j = 0; j < 4; ++j) {
    float asv = as1[c0 + 16 * j], adv = ad1[c0 + 16 * j];
    #pragma unroll
    for (int i = 0; i < 4; ++i) { ps[i][j] = acc[i][j] * asv; pd[i][j] = acc[i][j] * adv; }
  }
  #pragma unroll
  for (int m = 1; m <= 4; m <<= 1)
    #pragma unroll
    for (int i = 0; i < 4; ++i)
      #pragma unroll
      for (int j = 0; j < 4; ++j) {
        ps[i][j] += __shfl_xor(ps[i][j], m);
        pd[i][j] += __shfl_xor(pd[i][j], m);
      }
  if ((t & 7) == 0) {
    int half = (c0 >> 3) & 1;
    #pragma unroll
    for (int i = 0; i < 4; ++i) {
      int r = row0 + r4 + i;
      if (r < N_NODES) {
        #pragma unroll
        for (int j = 0; j < 4; ++j) {
          int h = 2 * j + half;
          al_s1[r * 8 + h] = ps[i][j];
          al_d1[r * 8 + h] = pd[i][j];
        }
      }
    }
  }
}

// ---------------------------------------------------------------- layer-1 aggregate (online softmax), wave per dst node
__global__ void agg1_kernel(const int* __restrict__ offs, const int* __restrict__ csr_src,
                            const float* __restrict__ al_s1, const float* __restrict__ al_d1,
                            const float* __restrict__ al_e1s, const float* __restrict__ xw1,
                            const float* __restrict__ b1, float* __restrict__ h1) {
  int node = blockIdx.x * 4 + (threadIdx.x >> 6);
  if (node >= N_NODES) return;
  int lane = threadIdx.x & 63;
  int h = lane >> 3;
  int base = offs[node], end = offs[node + 1];
  int degn = end - base;
  float adv = al_d1[node * 8 + h];
  float m = -INFINITY, ssum = 0.f, acc = 0.f, sume = 0.f;
  for (int j = base; j < end; ++j) {
    int sid = csr_src[j];
    float ae = al_e1s[(size_t)j * 8 + h];
    sume += ae;
    float a = al_s1[sid * 8 + h] + adv + ae;
    a = (a > 0.f) ? a : 0.2f * a;
    float nm = fmaxf(m, a);
    float sc = __expf(m - nm);
    float e = __expf(a - nm);
    ssum = ssum * sc + e;
    acc = acc * sc + e * xw1[(size_t)sid * 64 + lane];
    m = nm;
  }
  float aes = sume / (float)max(degn, 1);
  float a = al_s1[node * 8 + h] + adv + aes;
  a = (a > 0.f) ? a : 0.2f * a;
  float nm = fmaxf(m, a);
  float sc = __expf(m - nm);
  float e = __expf(a - nm);
  ssum = ssum * sc + e;
  acc = acc * sc + e * xw1[(size_t)node * 64 + lane];
  float o = acc / (ssum + 1e-16f) + b1[lane];
  h1[(size_t)node * 64 + lane] = (o > 0.f) ? o : expm1f(o);
}

// ---------------------------------------------------------------- gemm2: xw2 = h1 @ W2 (tiled), fused al_s2/al_d2
// tile: 64 rows x 128 cols, K=64. thread: rows r8..r8+7 (r8=(t>>5)*8), cols c0+32j (c0=t&31).
__global__ __launch_bounds__(256) void gemm2_kernel(
    const float* __restrict__ h1, const float* __restrict__ W2t,
    const float* __restrict__ as2, const float* __restrict__ ad2,
    float* __restrict__ xw2, float* __restrict__ al_s2, float* __restrict__ al_d2) {
  __shared__ float hl[64 * 68];    // 64 rows x (64 + 4 pad)
  __shared__ float wl[128 * 68];   // 128 cols x (64 + 4 pad)
  int t = threadIdx.x;
  int row0 = blockIdx.x * 64;
  const float4* hg = (const float4*)(h1 + (size_t)row0 * 64);
  const float4* wg = (const float4*)W2t;
  #pragma unroll
  for (int j = 0; j < 4; ++j) {   // 1024 float4s of h-tile
    int idx = t + j * 256;
    int r = idx >> 4, kq = idx & 15;
    float4 v = make_float4(0.f, 0.f, 0.f, 0.f);
    if (row0 + r < N_NODES) v = hg[r * 16 + kq];
    *(float4*)&hl[r * 68 + kq * 4] = v;
  }
  #pragma unroll
  for (int j = 0; j < 8; ++j) {   // 2048 float4s of W2t
    int idx = t + j * 256;
    int c = idx >> 4, kq = idx & 15;
    *(float4*)&wl[c * 68 + kq * 4] = wg[idx];
  }
  __syncthreads();
  int c0 = t & 31;
  int r8 = (t >> 5) * 8;
  float acc[8][4];
  #pragma unroll
  for (int i = 0; i < 8; ++i)
    #pragma unroll
    for (int j = 0; j < 4; ++j) acc[i][j] = 0.f;
  #pragma unroll 2
  for (int kq = 0; kq < 16; ++kq) {
    float4 xv[8], wv[4];
    #pragma unroll
    for (int i = 0; i < 8; ++i) xv[i] = *(const float4*)&hl[(r8 + i) * 68 + kq * 4];
    #pragma unroll
    for (int j = 0; j < 4; ++j) wv[j] = *(const float4*)&wl[(c0 + 32 * j) * 68 + kq * 4];
    #pragma unroll
    for (int i = 0; i < 8; ++i)
      #pragma unroll
      for (int j = 0; j < 4; ++j) {
        acc[i][j] = fmaf(xv[i].x, wv[j].x, acc[i][j]);
        acc[i][j] = fmaf(xv[i].y, wv[j].y, acc[i][j]);
        acc[i][j] = fmaf(xv[i].z, wv[j].z, acc[i][j]);
        acc[i][j] = fmaf(xv[i].w, wv[j].w, acc[i][j]);
      }
  }
  #pragma unroll
  for (int i = 0; i < 8; ++i) {
    int r = row0 + r8 + i;
    if (r < N_NODES) {
      #pragma unroll
      for (int j = 0; j < 4; ++j) xw2[(size_t)r * 128 + c0 + 32 * j] = acc[i][j];
    }
  }
  // fused al_s2/al_d2 (single head, full 128-col sum; reduce over c0  32 lanes)
  float ps[8], pd[8];
  #pragma unroll
  for (int i = 0; i < 8; ++i) { ps[i] = 0.f; pd[i] = 0.f; }
  #pragma unroll
  for (int j = 0; j < 4; ++j) {
    float asv = as2[c0 + 32 * j], adv = ad2[c0 + 32 * j];
    #pragma unroll
    for (int i = 0; i < 8; ++i) { ps[i] = fmaf(acc[i][j], asv, ps[i]); pd[i] = fmaf(acc[i][j], adv, pd[i]); }
  }
  #pragma unroll
  for (int m = 1; m <= 16; m <<= 1)
    #pragma unroll
    for (int i = 0; i < 8; ++i) {
      ps[i] += __shfl_xor(ps[i], m);
      pd[i] += __shfl_xor(pd[i], m);
    }
  if (c0 == 0) {
    #pragma unroll
    for (int i = 0; i < 8; ++i) {
      int r = row0 + r8 + i;
      if (r < N_NODES) { al_s2[r] = ps[i]; al_d2[r] = pd[i]; }
    }
  }
}

// ---------------------------------------------------------------- layer-2 aggregate, wave per dst node (128 ch, 2/lane)
__global__ void agg2_kernel(const int* __restrict__ offs, const int* __restrict__ csr_src,
                            const float* __restrict__ al_s2, const float* __restrict__ al_d2,
                            const float* __restrict__ al_e2s, const float* __restrict__ xw2,
                            const float* __restrict__ b2, float* __restrict__ h2) {
  int node = blockIdx.x * 4 + (threadIdx.x >> 6);
  if (node >= N_NODES) return;
  int lane = threadIdx.x & 63;
  int base = offs[node], end = offs[node + 1];
  int degn = end - base;
  float adv = al_d2[node];
  float m = -INFINITY, ssum = 0.f, acc0 = 0.f, acc1 = 0.f, sume = 0.f;
  for (int j = base; j < end; ++j) {
    int sid = csr_src[j];
    float ae = al_e2s[j];
    sume += ae;
    float a = al_s2[sid] + adv + ae;
    a = (a > 0.f) ? a : 0.2f * a;
    float nm = fmaxf(m, a);
    float sc = __expf(m - nm);
    float e = __expf(a - nm);
    ssum = ssum * sc + e;
    acc0 = acc0 * sc + e * xw2[(size_t)sid * 128 + lane];
    acc1 = acc1 * sc + e * xw2[(size_t)sid * 128 + 64 + lane];
    m = nm;
  }
  float aes = sume / (float)max(degn, 1);
  float a = al_s2[node] + adv + aes;
  a = (a > 0.f) ? a : 0.2f * a;
  float nm = fmaxf(m, a);
  float sc = __expf(m - nm);
  float e = __expf(a - nm);
  ssum = ssum * sc + e;
  acc0 = acc0 * sc + e * xw2[(size_t)node * 128 + lane];
  acc1 = acc1 * sc + e * xw2[(size_t)node * 128 + 64 + lane];
  float inv = 1.f / (ssum + 1e-16f);
  h2[(size_t)node * 128 + lane] = acc0 * inv + b2[lane];
  h2[(size_t)node * 128 + 64 + lane] = acc1 * inv + b2[lane + 64];
}

// ---------------------------------------------------------------- graph boundaries (batch is sorted)
__global__ void gstart_kernel(const int* __restrict__ batch, int* __restrict__ gstart) {
  int n = blockIdx.x * blockDim.x + threadIdx.x;
  if (n >= N_NODES) return;
  int b = batch[n];
  if (n == 0) {
    for (int g = 0; g <= b; ++g) gstart[g] = 0;
  } else {
    int pb = batch[n - 1];
    for (int g = pb + 1; g <= b; ++g) gstart[g] = n;
  }
  if (n == N_NODES - 1) {
    for (int g = b + 1; g <= NGRAPH; ++g) gstart[g] = N_NODES;
  }
}

// ---------------------------------------------------------------- mean pool, block per graph
__global__ void pool_kernel(const float* __restrict__ h2, const int* __restrict__ gstart,
                            float* __restrict__ out) {
  int g = blockIdx.x;
  int c = threadIdx.x;  // 128
  int s0 = gstart[g], s1 = gstart[g + 1];
  float s = 0.f;
  for (int r = s0; r < s1; ++r) s += h2[(size_t)r * 128 + c];
  out[g * 128 + c] = s / fmaxf((float)(s1 - s0), 1.f);
}

// ================================================================ launch
extern "C" void kernel_launch(void* const* d_in, const int* in_sizes, int n_in,
                              void* d_out, int out_size, void* d_ws, size_t ws_size,
                              hipStream_t stream) {
  const float* x      = (const float*)d_in[0];
  const int*   eidx   = (const int*)d_in[1];
  const float* ea     = (const float*)d_in[2];
  const int*   batch  = (const int*)d_in[3];
  const float* W1     = (const float*)d_in[4];
  const float* as1    = (const float*)d_in[5];
  const float* ad1    = (const float*)d_in[6];
  const float* ae1    = (const float*)d_in[7];
  const float* We1    = (const float*)d_in[8];
  const float* b1     = (const float*)d_in[9];
  const float* W2     = (const float*)d_in[10];
  const float* as2    = (const float*)d_in[11];
  const float* ad2    = (const float*)d_in[12];
  const float* ae2    = (const float*)d_in[13];
  const float* We2    = (const float*)d_in[14];
  const float* b2     = (const float*)d_in[15];
  float* out = (float*)d_out;

  const int* src = eidx;
  const int* dst = eidx + N_EDGES;

  char* base = (char*)d_ws;
  size_t o = 0;
  #define ALLOC(name, bytes) size_t name = o; o += (((size_t)(bytes)) + 255) & ~(size_t)255;
  ALLOC(o_degcnt, 2 * N_NODES * 4)            // deg at [0,N), cnt at [N,2N)
  ALLOC(o_offs,   (N_NODES + 1) * 4)
  ALLOC(o_bsum,   256 * 4)
  ALLOC(o_csr,    N_EDGES * 4)
  ALLOC(o_ale1,   (size_t)N_EDGES * 8 * 4)
  ALLOC(o_ale2,   N_EDGES * 4)
  ALLOC(o_w1t,    64 * 128 * 4)
  ALLOC(o_w2t,    128 * 64 * 4)
  ALLOC(o_xw1,    (size_t)N_NODES * 64 * 4)
  ALLOC(o_als1,   N_NODES * 8 * 4)
  ALLOC(o_ald1,   N_NODES * 8 * 4)
  ALLOC(o_h1,     (size_t)N_NODES * 64 * 4)
  ALLOC(o_xw2,    (size_t)N_NODES * 128 * 4)
  ALLOC(o_als2,   N_NODES * 4)
  ALLOC(o_ald2,   N_NODES * 4)
  ALLOC(o_h2,     (size_t)N_NODES * 128 * 4)
  ALLOC(o_gs,     (NGRAPH + 1) * 4)
  #undef ALLOC

  int*   deg     = (int*)(base + o_degcnt);
  int*   cnt     = deg + N_NODES;
  int*   offs    = (int*)(base + o_offs);
  int*   bsum    = (int*)(base + o_bsum);
  int*   csr_src = (int*)(base + o_csr);
  float* al_e1s  = (float*)(base + o_ale1);
  float* al_e2s  = (float*)(base + o_ale2);
  float* W1t     = (float*)(base + o_w1t);
  float* W2t     = (float*)(base + o_w2t);
  float* xw1     = (float*)(base + o_xw1);
  float* al_s1   = (float*)(base + o_als1);
  float* al_d1   = (float*)(base + o_ald1);
  float* h1      = (float*)(base + o_h1);
  float* xw2     = (float*)(base + o_xw2);
  float* al_s2   = (float*)(base + o_als2);
  float* al_d2   = (float*)(base + o_ald2);
  float* h2      = (float*)(base + o_h2);
  int*   gstart  = (int*)(base + o_gs);

  hipMemsetAsync(deg, 0, (size_t)2 * N_NODES * 4, stream);

  prep_kernel<<<32, 256, 0, stream>>>(W1, W2, W1t, W2t);
  hist_kernel<<<1024, 256, 0, stream>>>(dst, deg);
  scan1_kernel<<<196, 256, 0, stream>>>(deg, offs, bsum);
  scan2_kernel<<<1, 256, 0, stream>>>(bsum);
  scan3_kernel<<<196, 256, 0, stream>>>(bsum, offs);
  scatter_kernel<<<2048, 256, 0, stream>>>(src, dst, ea, We1, ae1, We2, ae2,
                                           offs, cnt, csr_src, al_e1s, al_e2s);
  gemm1_kernel<<<(N_NODES + 63) / 64, 256, 0, stream>>>(x, W1t, as1, ad1, xw1, al_s1, al_d1);
  agg1_kernel<<<(N_NODES + 3) / 4, 256, 0, stream>>>(offs, csr_src, al_s1, al_d1,
                                                     al_e1s, xw1, b1, h1);
  gemm2_kernel<<<(N_NODES + 63) / 64, 256, 0, stream>>>(h1, W2t, as2, ad2, xw2, al_s2, al_d2);
  agg2_kernel<<<(N_NODES + 3) / 4, 256, 0, stream>>>(offs, csr_src, al_s2, al_d2,
                                                     al_e2s, xw2, b2, h2);
  gstart_kernel<<<(N_NODES + 255) / 256, 256, 0, stream>>>(batch, gstart);
  pool_kernel<<<NGRAPH, 128, 0, stream>>>(h2, gstart, out);
}

// Round 7
// 512.865 us; speedup vs baseline: 1.7769x; 1.1445x over previous
//
#include <hip/hip_runtime.h>
#include <hip/hip_bf16.h>
#include <math.h>

#define N_NODES 50000
#define N_EDGES 800000
#define F_IN    128
#define ED_DIM  16
#define D1      64    /* H1*C1 */
#define NGRAPH  256
#define OUT_C   128

// ---------------------------------------------------------------- prep: transpose W1->W1t[64][128], W2->W2t[128][64]
__global__ void prep_kernel(const float* __restrict__ W1, const float* __restrict__ W2,
                            float* __restrict__ W1t, float* __restrict__ W2t) {
  int t = blockIdx.x * 256 + threadIdx.x;
  if (t < 64 * 128) {
    int k = t >> 6, c = t & 63;          // W1[k*64+c], k<128
    W1t[c * 128 + k] = W1[t];
    int k2 = t >> 7, c2 = t & 127;       // W2[k*128+c], k<64
    W2t[c2 * 64 + k2] = W2[t];
  }
}

// ---------------------------------------------------------------- histogram
__global__ void hist_kernel(const int* __restrict__ dst, int* __restrict__ deg) {
  int i = blockIdx.x * blockDim.x + threadIdx.x;
  int stride = gridDim.x * blockDim.x;
  for (; i < N_EDGES; i += stride) atomicAdd(&deg[dst[i]], 1);
}

// ---------------------------------------------------------------- hierarchical scan (3 kernels)
__global__ void scan1_kernel(const int* __restrict__ deg, int* __restrict__ offs,
                             int* __restrict__ bsum) {
  __shared__ int sh[256];
  int b = blockIdx.x, t = threadIdx.x, i = b * 256 + t;
  int v = (i < N_NODES) ? deg[i] : 0;
  sh[t] = v;
  __syncthreads();
  for (int o = 1; o < 256; o <<= 1) {
    int tv = (t >= o) ? sh[t - o] : 0;
    __syncthreads();
    sh[t] += tv;
    __syncthreads();
  }
  if (i < N_NODES) offs[i + 1] = sh[t];
  if (t == 255) bsum[b] = sh[255];
}

__global__ void scan2_kernel(int* __restrict__ bsum) {  // 196 entries, 1 block
  __shared__ int sh[256];
  int t = threadIdx.x;
  sh[t] = (t < 196) ? bsum[t] : 0;
  __syncthreads();
  for (int o = 1; o < 256; o <<= 1) {
    int tv = (t >= o) ? sh[t - o] : 0;
    __syncthreads();
    sh[t] += tv;
    __syncthreads();
  }
  if (t < 196) bsum[t] = (t > 0) ? sh[t - 1] : 0;  // exclusive
}

__global__ void scan3_kernel(const int* __restrict__ bsum, int* __restrict__ offs) {
  int b = blockIdx.x, t = threadIdx.x, i = b * 256 + t;
  if (i < N_NODES) offs[i + 1] += bsum[b];
  if (i == 0) offs[0] = 0;
}

// ---------------------------------------------------------------- scatter edges to CSR, packed 64B record per edge:
// rec[pos*16]: [0]=sid(bits) [1..8]=al_e1 heads [9]=al_e2 [10..15]=pad
__global__ void scatter_kernel(const int* __restrict__ src, const int* __restrict__ dst,
                               const float* __restrict__ ea,
                               const float* __restrict__ We1, const float* __restrict__ ae1,
                               const float* __restrict__ We2, const float* __restrict__ ae2,
                               const int* __restrict__ offs, int* __restrict__ cnt,
                               float* __restrict__ rec) {
  __shared__ float M1s[16][8];
  __shared__ float M2s[16];
  int t = threadIdx.x;
  if (t < 128) {
    int d = t >> 3, h = t & 7;
    float s = 0.f;
    #pragma unroll
    for (int c = 0; c < 8; ++c) s = fmaf(We1[d * 64 + h * 8 + c], ae1[h * 8 + c], s);
    M1s[d][h] = s;
  } else if (t < 144) {
    int d = t - 128;
    float s = 0.f;
    for (int c = 0; c < 128; ++c) s = fmaf(We2[d * 128 + c], ae2[c], s);
    M2s[d] = s;
  }
  __syncthreads();
  int i = blockIdx.x * blockDim.x + t;
  int stride = gridDim.x * blockDim.x;
  for (; i < N_EDGES; i += stride) {
    int s = src[i], d = dst[i];
    float e[16];
    const float4* ea4 = (const float4*)(ea + (size_t)i * 16);
    #pragma unroll
    for (int q = 0; q < 4; ++q) {
      float4 v = ea4[q];
      e[q * 4] = v.x; e[q * 4 + 1] = v.y; e[q * 4 + 2] = v.z; e[q * 4 + 3] = v.w;
    }
    int pos = offs[d] + atomicAdd(&cnt[d], 1);
    float r[8];
    #pragma unroll
    for (int h = 0; h < 8; ++h) {
      float sacc = 0.f;
      #pragma unroll
      for (int dd = 0; dd < 16; ++dd) sacc = fmaf(e[dd], M1s[dd][h], sacc);
      r[h] = sacc;
    }
    float s2 = 0.f;
    #pragma unroll
    for (int dd = 0; dd < 16; ++dd) s2 = fmaf(e[dd], M2s[dd], s2);
    float4* o4 = (float4*)(rec + (size_t)pos * 16);
    o4[0] = make_float4(__int_as_float(s), r[0], r[1], r[2]);
    o4[1] = make_float4(r[3], r[4], r[5], r[6]);
    o4[2] = make_float4(r[7], s2, 0.f, 0.f);
    o4[3] = make_float4(0.f, 0.f, 0.f, 0.f);
  }
}

// ---------------------------------------------------------------- gemm1: xw1 = x @ W1 (tiled), fused al_s1/al_d1
__global__ __launch_bounds__(256) void gemm1_kernel(
    const float* __restrict__ x, const float* __restrict__ W1t,
    const float* __restrict__ as1, const float* __restrict__ ad1,
    float* __restrict__ xw1, float* __restrict__ al_s1, float* __restrict__ al_d1) {
  __shared__ float xl[64 * 132];   // 64 rows x (128 + 4 pad)
  __shared__ float wl[64 * 132];   // 64 cols x (128 + 4 pad)
  int t = threadIdx.x;
  int row0 = blockIdx.x * 64;
  const float4* xg = (const float4*)(x + (size_t)row0 * 128);
  const float4* wg = (const float4*)W1t;
  #pragma unroll
  for (int j = 0; j < 8; ++j) {
    int idx = t + j * 256;          // float4 index in 64x32 grid
    int r = idx >> 5, kq = idx & 31;
    float4 v = make_float4(0.f, 0.f, 0.f, 0.f);
    if (row0 + r < N_NODES) v = xg[r * 32 + kq];
    *(float4*)&xl[r * 132 + kq * 4] = v;
    *(float4*)&wl[(idx >> 5) * 132 + kq * 4] = wg[idx];
  }
  __syncthreads();
  int c0 = t & 15;
  int r4 = (t >> 4) * 4;
  float acc[4][4];
  #pragma unroll
  for (int i = 0; i < 4; ++i)
    #pragma unroll
    for (int j = 0; j < 4; ++j) acc[i][j] = 0.f;
  #pragma unroll 4
  for (int kq = 0; kq < 32; ++kq) {
    float4 xv[4], wv[4];
    #pragma unroll
    for (int i = 0; i < 4; ++i) xv[i] = *(const float4*)&xl[(r4 + i) * 132 + kq * 4];
    #pragma unroll
    for (int j = 0; j < 4; ++j) wv[j] = *(const float4*)&wl[(c0 + 16 * j) * 132 + kq * 4];
    #pragma unroll
    for (int i = 0; i < 4; ++i)
      #pragma unroll
      for (int j = 0; j < 4; ++j) {
        acc[i][j] = fmaf(xv[i].x, wv[j].x, acc[i][j]);
        acc[i][j] = fmaf(xv[i].y, wv[j].y, acc[i][j]);
        acc[i][j] = fmaf(xv[i].z, wv[j].z, acc[i][j]);
        acc[i][j] = fmaf(xv[i].w, wv[j].w, acc[i][j]);
      }
  }
  #pragma unroll
  for (int i = 0; i < 4; ++i) {
    int r = row0 + r4 + i;
    if (r < N_NODES) {
      #pragma unroll
      for (int j = 0; j < 4; ++j) xw1[(size_t)r * 64 + c0 + 16 * j] = acc[i][j];
    }
  }
  float ps[4][4], pd[4][4];
  #pragma unroll
  for (int j = 0; j < 4; ++j) {
    float asv = as1[c0 + 16 * j], adv = ad1[c0 + 16 * j];
    #pragma unroll
    for (int i = 0; i < 4; ++i) { ps[i][j] = acc[i][j] * asv; pd[i][j] = acc[i][j] * adv; }
  }
  #pragma unroll
  for (int m = 1; m <= 4; m <<= 1)
    #pragma unroll
    for (int i = 0; i < 4; ++i)
      #pragma unroll
      for (int j = 0; j < 4; ++j) {
        ps[i][j] += __shfl_xor(ps[i][j], m);
        pd[i][j] += __shfl_xor(pd[i][j], m);
      }
  if ((t & 7) == 0) {
    int half = (c0 >> 3) & 1;
    #pragma unroll
    for (int i = 0; i < 4; ++i) {
      int r = row0 + r4 + i;
      if (r < N_NODES) {
        #pragma unroll
        for (int j = 0; j < 4; ++j) {
          int h = 2 * j + half;
          al_s1[r * 8 + h] = ps[i][j];
          al_d1[r * 8 + h] = pd[i][j];
        }
      }
    }
  }
}

// ---------------------------------------------------------------- layer-1 aggregate (online softmax, unroll-2), wave/node
__global__ void agg1_kernel(const int* __restrict__ offs, const float* __restrict__ rec,
                            const float* __restrict__ al_s1, const float* __restrict__ al_d1,
                            const float* __restrict__ xw1,
                            const float* __restrict__ b1, float* __restrict__ h1) {
  int node = blockIdx.x * 4 + (threadIdx.x >> 6);
  if (node >= N_NODES) return;
  int lane = threadIdx.x & 63;
  int h = lane >> 3;
  int base = offs[node], end = offs[node + 1];
  int degn = end - base;
  float adv = al_d1[node * 8 + h];
  float m = -INFINITY, ssum = 0.f, acc = 0.f, sume = 0.f;
  int j = base;
  for (; j + 1 < end; j += 2) {
    const float* r0 = rec + (size_t)j * 16;
    const float* r1 = r0 + 16;
    int s0 = __float_as_int(r0[0]); float ae0 = r0[1 + h];
    int s1 = __float_as_int(r1[0]); float ae1 = r1[1 + h];
    float x0 = xw1[(size_t)s0 * 64 + lane];
    float x1 = xw1[(size_t)s1 * 64 + lane];
    float a0 = al_s1[s0 * 8 + h] + adv + ae0;
    float a1 = al_s1[s1 * 8 + h] + adv + ae1;
    sume += ae0 + ae1;
    a0 = (a0 > 0.f) ? a0 : 0.2f * a0;
    a1 = (a1 > 0.f) ? a1 : 0.2f * a1;
    float nm = fmaxf(m, fmaxf(a0, a1));
    float sc = __expf(m - nm), e0 = __expf(a0 - nm), e1 = __expf(a1 - nm);
    ssum = ssum * sc + e0 + e1;
    acc = acc * sc + e0 * x0 + e1 * x1;
    m = nm;
  }
  if (j < end) {
    const float* r0 = rec + (size_t)j * 16;
    int s0 = __float_as_int(r0[0]); float ae0 = r0[1 + h];
    float x0 = xw1[(size_t)s0 * 64 + lane];
    float a0 = al_s1[s0 * 8 + h] + adv + ae0;
    sume += ae0;
    a0 = (a0 > 0.f) ? a0 : 0.2f * a0;
    float nm = fmaxf(m, a0);
    float sc = __expf(m - nm), e0 = __expf(a0 - nm);
    ssum = ssum * sc + e0;
    acc = acc * sc + e0 * x0;
    m = nm;
  }
  // self loop: al_e_self = mean of incoming al_e (linearity of ea @ M1)
  float aes = sume / (float)max(degn, 1);
  float a = al_s1[node * 8 + h] + adv + aes;
  a = (a > 0.f) ? a : 0.2f * a;
  float nm = fmaxf(m, a);
  float sc = __expf(m - nm);
  float e = __expf(a - nm);
  ssum = ssum * sc + e;
  acc = acc * sc + e * xw1[(size_t)node * 64 + lane];
  float o = acc / (ssum + 1e-16f) + b1[lane];
  h1[(size_t)node * 64 + lane] = (o > 0.f) ? o : expm1f(o);
}

// ---------------------------------------------------------------- gemm2: xw2 = h1 @ W2 (tiled), fused al_s2/al_d2
__global__ __launch_bounds__(256) void gemm2_kernel(
    const float* __restrict__ h1, const float* __restrict__ W2t,
    const float* __restrict__ as2, const float* __restrict__ ad2,
    float* __restrict__ xw2, float* __restrict__ al_s2, float* __restrict__ al_d2) {
  __shared__ float hl[64 * 68];    // 64 rows x (64 + 4 pad)
  __shared__ float wl[128 * 68];   // 128 cols x (64 + 4 pad)
  int t = threadIdx.x;
  int row0 = blockIdx.x * 64;
  const float4* hg = (const float4*)(h1 + (size_t)row0 * 64);
  const float4* wg = (const float4*)W2t;
  #pragma unroll
  for (int j = 0; j < 4; ++j) {   // 1024 float4s of h-tile
    int idx = t + j * 256;
    int r = idx >> 4, kq = idx & 15;
    float4 v = make_float4(0.f, 0.f, 0.f, 0.f);
    if (row0 + r < N_NODES) v = hg[r * 16 + kq];
    *(float4*)&hl[r * 68 + kq * 4] = v;
  }
  #pragma unroll
  for (int j = 0; j < 8; ++j) {   // 2048 float4s of W2t
    int idx = t + j * 256;
    int c = idx >> 4, kq = idx & 15;
    *(float4*)&wl[c * 68 + kq * 4] = wg[idx];
  }
  __syncthreads();
  int c0 = t & 31;
  int r8 = (t >> 5) * 8;
  float acc[8][4];
  #pragma unroll
  for (int i = 0; i < 8; ++i)
    #pragma unroll
    for (int j = 0; j < 4; ++j) acc[i][j] = 0.f;
  #pragma unroll 2
  for (int kq = 0; kq < 16; ++kq) {
    float4 xv[8], wv[4];
    #pragma unroll
    for (int i = 0; i < 8; ++i) xv[i] = *(const float4*)&hl[(r8 + i) * 68 + kq * 4];
    #pragma unroll
    for (int j = 0; j < 4; ++j) wv[j] = *(const float4*)&wl[(c0 + 32 * j) * 68 + kq * 4];
    #pragma unroll
    for (int i = 0; i < 8; ++i)
      #pragma unroll
      for (int j = 0; j < 4; ++j) {
        acc[i][j] = fmaf(xv[i].x, wv[j].x, acc[i][j]);
        acc[i][j] = fmaf(xv[i].y, wv[j].y, acc[i][j]);
        acc[i][j] = fmaf(xv[i].z, wv[j].z, acc[i][j]);
        acc[i][j] = fmaf(xv[i].w, wv[j].w, acc[i][j]);
      }
  }
  #pragma unroll
  for (int i = 0; i < 8; ++i) {
    int r = row0 + r8 + i;
    if (r < N_NODES) {
      #pragma unroll
      for (int j = 0; j < 4; ++j) xw2[(size_t)r * 128 + c0 + 32 * j] = acc[i][j];
    }
  }
  float ps[8], pd[8];
  #pragma unroll
  for (int i = 0; i < 8; ++i) { ps[i] = 0.f; pd[i] = 0.f; }
  #pragma unroll
  for (int j = 0; j < 4; ++j) {
    float asv = as2[c0 + 32 * j], adv = ad2[c0 + 32 * j];
    #pragma unroll
    for (int i = 0; i < 8; ++i) { ps[i] = fmaf(acc[i][j], asv, ps[i]); pd[i] = fmaf(acc[i][j], adv, pd[i]); }
  }
  #pragma unroll
  for (int m = 1; m <= 16; m <<= 1)
    #pragma unroll
    for (int i = 0; i < 8; ++i) {
      ps[i] += __shfl_xor(ps[i], m);
      pd[i] += __shfl_xor(pd[i], m);
    }
  if (c0 == 0) {
    #pragma unroll
    for (int i = 0; i < 8; ++i) {
      int r = row0 + r8 + i;
      if (r < N_NODES) { al_s2[r] = ps[i]; al_d2[r] = pd[i]; }
    }
  }
}

// ---------------------------------------------------------------- layer-2 aggregate (online softmax, unroll-2), wave/node
__global__ void agg2_kernel(const int* __restrict__ offs, const float* __restrict__ rec,
                            const float* __restrict__ al_s2, const float* __restrict__ al_d2,
                            const float* __restrict__ xw2,
                            const float* __restrict__ b2, float* __restrict__ h2) {
  int node = blockIdx.x * 4 + (threadIdx.x >> 6);
  if (node >= N_NODES) return;
  int lane = threadIdx.x & 63;
  int base = offs[node], end = offs[node + 1];
  int degn = end - base;
  float adv = al_d2[node];
  float m = -INFINITY, ssum = 0.f, acc0 = 0.f, acc1 = 0.f, sume = 0.f;
  int j = base;
  for (; j + 1 < end; j += 2) {
    const float* r0 = rec + (size_t)j * 16;
    const float* r1 = r0 + 16;
    int s0 = __float_as_int(r0[0]); float ae0 = r0[9];
    int s1 = __float_as_int(r1[0]); float ae1 = r1[9];
    float x0a = xw2[(size_t)s0 * 128 + lane];
    float x0b = xw2[(size_t)s0 * 128 + 64 + lane];
    float x1a = xw2[(size_t)s1 * 128 + lane];
    float x1b = xw2[(size_t)s1 * 128 + 64 + lane];
    float a0 = al_s2[s0] + adv + ae0;
    float a1 = al_s2[s1] + adv + ae1;
    sume += ae0 + ae1;
    a0 = (a0 > 0.f) ? a0 : 0.2f * a0;
    a1 = (a1 > 0.f) ? a1 : 0.2f * a1;
    float nm = fmaxf(m, fmaxf(a0, a1));
    float sc = __expf(m - nm), e0 = __expf(a0 - nm), e1 = __expf(a1 - nm);
    ssum = ssum * sc + e0 + e1;
    acc0 = acc0 * sc + e0 * x0a + e1 * x1a;
    acc1 = acc1 * sc + e0 * x0b + e1 * x1b;
    m = nm;
  }
  if (j < end) {
    const float* r0 = rec + (size_t)j * 16;
    int s0 = __float_as_int(r0[0]); float ae0 = r0[9];
    float x0a = xw2[(size_t)s0 * 128 + lane];
    float x0b = xw2[(size_t)s0 * 128 + 64 + lane];
    float a0 = al_s2[s0] + adv + ae0;
    sume += ae0;
    a0 = (a0 > 0.f) ? a0 : 0.2f * a0;
    float nm = fmaxf(m, a0);
    float sc = __expf(m - nm), e0 = __expf(a0 - nm);
    ssum = ssum * sc + e0;
    acc0 = acc0 * sc + e0 * x0a;
    acc1 = acc1 * sc + e0 * x0b;
    m = nm;
  }
  float aes = sume / (float)max(degn, 1);
  float a = al_s2[node] + adv + aes;
  a = (a > 0.f) ? a : 0.2f * a;
  float nm = fmaxf(m, a);
  float sc = __expf(m - nm);
  float e = __expf(a - nm);
  ssum = ssum * sc + e;
  acc0 = acc0 * sc + e * xw2[(size_t)node * 128 + lane];
  acc1 = acc1 * sc + e * xw2[(size_t)node * 128 + 64 + lane];
  float inv = 1.f / (ssum + 1e-16f);
  h2[(size_t)node * 128 + lane] = acc0 * inv + b2[lane];
  h2[(size_t)node * 128 + 64 + lane] = acc1 * inv + b2[lane + 64];
}

// ---------------------------------------------------------------- graph boundaries (batch is sorted)
__global__ void gstart_kernel(const int* __restrict__ batch, int* __restrict__ gstart) {
  int n = blockIdx.x * blockDim.x + threadIdx.x;
  if (n >= N_NODES) return;
  int b = batch[n];
  if (n == 0) {
    for (int g = 0; g <= b; ++g) gstart[g] = 0;
  } else {
    int pb = batch[n - 1];
    for (int g = pb + 1; g <= b; ++g) gstart[g] = n;
  }
  if (n == N_NODES - 1) {
    for (int g = b + 1; g <= NGRAPH; ++g) gstart[g] = N_NODES;
  }
}

// ---------------------------------------------------------------- mean pool, block per graph
__global__ void pool_kernel(const float* __restrict__ h2, const int* __restrict__ gstart,
                            float* __restrict__ out) {
  int g = blockIdx.x;
  int c = threadIdx.x;  // 128
  int s0 = gstart[g], s1 = gstart[g + 1];
  float s = 0.f;
  for (int r = s0; r < s1; ++r) s += h2[(size_t)r * 128 + c];
  out[g * 128 + c] = s / fmaxf((float)(s1 - s0), 1.f);
}

// ================================================================ launch
extern "C" void kernel_launch(void* const* d_in, const int* in_sizes, int n_in,
                              void* d_out, int out_size, void* d_ws, size_t ws_size,
                              hipStream_t stream) {
  const float* x      = (const float*)d_in[0];
  const int*   eidx   = (const int*)d_in[1];
  const float* ea     = (const float*)d_in[2];
  const int*   batch  = (const int*)d_in[3];
  const float* W1     = (const float*)d_in[4];
  const float* as1    = (const float*)d_in[5];
  const float* ad1    = (const float*)d_in[6];
  const float* ae1    = (const float*)d_in[7];
  const float* We1    = (const float*)d_in[8];
  const float* b1     = (const float*)d_in[9];
  const float* W2     = (const float*)d_in[10];
  const float* as2    = (const float*)d_in[11];
  const float* ad2    = (const float*)d_in[12];
  const float* ae2    = (const float*)d_in[13];
  const float* We2    = (const float*)d_in[14];
  const float* b2     = (const float*)d_in[15];
  float* out = (float*)d_out;

  const int* src = eidx;
  const int* dst = eidx + N_EDGES;

  char* base = (char*)d_ws;
  size_t o = 0;
  #define ALLOC(name, bytes) size_t name = o; o += (((size_t)(bytes)) + 255) & ~(size_t)255;
  ALLOC(o_degcnt, 2 * N_NODES * 4)            // deg at [0,N), cnt at [N,2N)
  ALLOC(o_offs,   (N_NODES + 1) * 4)
  ALLOC(o_bsum,   256 * 4)
  ALLOC(o_rec,    (size_t)N_EDGES * 16 * 4)   // packed 64B records
  ALLOC(o_w1t,    64 * 128 * 4)
  ALLOC(o_w2t,    128 * 64 * 4)
  ALLOC(o_xw1,    (size_t)N_NODES * 64 * 4)   // also reused as h2 later
  ALLOC(o_als1,   N_NODES * 8 * 4)
  ALLOC(o_ald1,   N_NODES * 8 * 4)
  ALLOC(o_h1,     (size_t)N_NODES * 64 * 4)
  ALLOC(o_xw2,    (size_t)N_NODES * 128 * 4)
  ALLOC(o_als2,   N_NODES * 4)
  ALLOC(o_ald2,   N_NODES * 4)
  ALLOC(o_gs,     (NGRAPH + 1) * 4)
  #undef ALLOC

  int*   deg     = (int*)(base + o_degcnt);
  int*   cnt     = deg + N_NODES;
  int*   offs    = (int*)(base + o_offs);
  int*   bsum    = (int*)(base + o_bsum);
  float* rec     = (float*)(base + o_rec);
  float* W1t     = (float*)(base + o_w1t);
  float* W2t     = (float*)(base + o_w2t);
  float* xw1     = (float*)(base + o_xw1);
  float* al_s1   = (float*)(base + o_als1);
  float* al_d1   = (float*)(base + o_ald1);
  float* h1      = (float*)(base + o_h1);
  float* xw2     = (float*)(base + o_xw2);
  float* al_s2   = (float*)(base + o_als2);
  float* al_d2   = (float*)(base + o_ald2);
  float* h2      = (float*)(base + o_xw1);   // alias: xw1+h1 dead after gemm2
  int*   gstart  = (int*)(base + o_gs);

  hipMemsetAsync(deg, 0, (size_t)2 * N_NODES * 4, stream);

  prep_kernel<<<32, 256, 0, stream>>>(W1, W2, W1t, W2t);
  hist_kernel<<<1024, 256, 0, stream>>>(dst, deg);
  scan1_kernel<<<196, 256, 0, stream>>>(deg, offs, bsum);
  scan2_kernel<<<1, 256, 0, stream>>>(bsum);
  scan3_kernel<<<196, 256, 0, stream>>>(bsum, offs);
  scatter_kernel<<<2048, 256, 0, stream>>>(src, dst, ea, We1, ae1, We2, ae2,
                                           offs, cnt, rec);
  gemm1_kernel<<<(N_NODES + 63) / 64, 256, 0, stream>>>(x, W1t, as1, ad1, xw1, al_s1, al_d1);
  agg1_kernel<<<(N_NODES + 3) / 4, 256, 0, stream>>>(offs, rec, al_s1, al_d1, xw1, b1, h1);
  gemm2_kernel<<<(N_NODES + 63) / 64, 256, 0, stream>>>(h1, W2t, as2, ad2, xw2, al_s2, al_d2);
  agg2_kernel<<<(N_NODES + 3) / 4, 256, 0, stream>>>(offs, rec, al_s2, al_d2, xw2, b2, h2);
  gstart_kernel<<<(N_NODES + 255) / 256, 256, 0, stream>>>(batch, gstart);
  pool_kernel<<<NGRAPH, 128, 0, stream>>>(h2, gstart, out);
}

// Round 9
// 487.136 us; speedup vs baseline: 1.8707x; 1.0528x over previous
//
#include <hip/hip_runtime.h>
#include <hip/hip_bf16.h>
#include <math.h>

#define N_NODES 50000
#define N_EDGES 800000
#define F_IN    128
#define ED_DIM  16
#define D1      64    /* H1*C1 */
#define NGRAPH  256
#define OUT_C   128

// ---------------------------------------------------------------- prep: transpose W1->W1t[64][128], W2->W2t[128][64]
__global__ void prep_kernel(const float* __restrict__ W1, const float* __restrict__ W2,
                            float* __restrict__ W1t, float* __restrict__ W2t) {
  int t = blockIdx.x * 256 + threadIdx.x;
  if (t < 64 * 128) {
    int k = t >> 6, c = t & 63;          // W1[k*64+c], k<128
    W1t[c * 128 + k] = W1[t];
    int k2 = t >> 7, c2 = t & 127;       // W2[k*128+c], k<64
    W2t[c2 * 64 + k2] = W2[t];
  }
}

// ---------------------------------------------------------------- fused histogram + edge-order attention logits
// ale1[i*8+h] = ea[i,:]·M1[:,h];  ale2[i] = ea[i,:]·M2.  All sequential I/O.
__global__ void histcalc_kernel(const int* __restrict__ dst, const float* __restrict__ ea,
                                const float* __restrict__ We1, const float* __restrict__ ae1w,
                                const float* __restrict__ We2, const float* __restrict__ ae2w,
                                int* __restrict__ deg,
                                float* __restrict__ ale1, float* __restrict__ ale2) {
  __shared__ float M1s[16][8];
  __shared__ float M2s[16];
  int t = threadIdx.x;
  if (t < 128) {
    int d = t >> 3, h = t & 7;
    float s = 0.f;
    #pragma unroll
    for (int c = 0; c < 8; ++c) s = fmaf(We1[d * 64 + h * 8 + c], ae1w[h * 8 + c], s);
    M1s[d][h] = s;
  } else if (t < 144) {
    int d = t - 128;
    float s = 0.f;
    for (int c = 0; c < 128; ++c) s = fmaf(We2[d * 128 + c], ae2w[c], s);
    M2s[d] = s;
  }
  __syncthreads();
  int i = blockIdx.x * blockDim.x + t;
  int stride = gridDim.x * blockDim.x;
  for (; i < N_EDGES; i += stride) {
    atomicAdd(&deg[dst[i]], 1);
    float e[16];
    const float4* ea4 = (const float4*)(ea + (size_t)i * 16);
    #pragma unroll
    for (int q = 0; q < 4; ++q) {
      float4 v = ea4[q];
      e[q * 4] = v.x; e[q * 4 + 1] = v.y; e[q * 4 + 2] = v.z; e[q * 4 + 3] = v.w;
    }
    float r[8];
    #pragma unroll
    for (int h = 0; h < 8; ++h) {
      float sacc = 0.f;
      #pragma unroll
      for (int dd = 0; dd < 16; ++dd) sacc = fmaf(e[dd], M1s[dd][h], sacc);
      r[h] = sacc;
    }
    float s2 = 0.f;
    #pragma unroll
    for (int dd = 0; dd < 16; ++dd) s2 = fmaf(e[dd], M2s[dd], s2);
    float4* o4 = (float4*)(ale1 + (size_t)i * 8);
    o4[0] = make_float4(r[0], r[1], r[2], r[3]);
    o4[1] = make_float4(r[4], r[5], r[6], r[7]);
    ale2[i] = s2;
  }
}

// ---------------------------------------------------------------- hierarchical scan (3 kernels)
__global__ void scan1_kernel(const int* __restrict__ deg, int* __restrict__ offs,
                             int* __restrict__ bsum) {
  __shared__ int sh[256];
  int b = blockIdx.x, t = threadIdx.x, i = b * 256 + t;
  int v = (i < N_NODES) ? deg[i] : 0;
  sh[t] = v;
  __syncthreads();
  for (int o = 1; o < 256; o <<= 1) {
    int tv = (t >= o) ? sh[t - o] : 0;
    __syncthreads();
    sh[t] += tv;
    __syncthreads();
  }
  if (i < N_NODES) offs[i + 1] = sh[t];
  if (t == 255) bsum[b] = sh[255];
}

__global__ void scan2_kernel(int* __restrict__ bsum) {  // 196 entries, 1 block
  __shared__ int sh[256];
  int t = threadIdx.x;
  sh[t] = (t < 196) ? bsum[t] : 0;
  __syncthreads();
  for (int o = 1; o < 256; o <<= 1) {
    int tv = (t >= o) ? sh[t - o] : 0;
    __syncthreads();
    sh[t] += tv;
    __syncthreads();
  }
  if (t < 196) bsum[t] = (t > 0) ? sh[t - 1] : 0;  // exclusive
}

__global__ void scan3_kernel(const int* __restrict__ bsum, int* __restrict__ offs) {
  int b = blockIdx.x, t = threadIdx.x, i = b * 256 + t;
  if (i < N_NODES) offs[i + 1] += bsum[b];
  if (i == 0) offs[0] = 0;
}

// ---------------------------------------------------------------- scatter indices only: csr[pos] = {src, eid} (8B)
__global__ void scatter_kernel(const int* __restrict__ src, const int* __restrict__ dst,
                               const int* __restrict__ offs, int* __restrict__ cnt,
                               int2* __restrict__ csr) {
  int i = blockIdx.x * blockDim.x + threadIdx.x;
  int stride = gridDim.x * blockDim.x;
  for (; i < N_EDGES; i += stride) {
    int d = dst[i];
    int pos = offs[d] + atomicAdd(&cnt[d], 1);
    csr[pos] = make_int2(src[i], i);
  }
}

// ---------------------------------------------------------------- gemm1: xw1 = x @ W1 (tiled), fused al_s1/al_d1
__global__ __launch_bounds__(256) void gemm1_kernel(
    const float* __restrict__ x, const float* __restrict__ W1t,
    const float* __restrict__ as1, const float* __restrict__ ad1,
    float* __restrict__ xw1, float* __restrict__ al_s1, float* __restrict__ al_d1) {
  __shared__ float xl[64 * 132];   // 64 rows x (128 + 4 pad)
  __shared__ float wl[64 * 132];   // 64 cols x (128 + 4 pad)
  int t = threadIdx.x;
  int row0 = blockIdx.x * 64;
  const float4* xg = (const float4*)(x + (size_t)row0 * 128);
  const float4* wg = (const float4*)W1t;
  #pragma unroll
  for (int j = 0; j < 8; ++j) {
    int idx = t + j * 256;          // float4 index in 64x32 grid
    int r = idx >> 5, kq = idx & 31;
    float4 v = make_float4(0.f, 0.f, 0.f, 0.f);
    if (row0 + r < N_NODES) v = xg[r * 32 + kq];
    *(float4*)&xl[r * 132 + kq * 4] = v;
    *(float4*)&wl[(idx >> 5) * 132 + kq * 4] = wg[idx];
  }
  __syncthreads();
  int c0 = t & 15;
  int r4 = (t >> 4) * 4;
  float acc[4][4];
  #pragma unroll
  for (int i = 0; i < 4; ++i)
    #pragma unroll
    for (int j = 0; j < 4; ++j) acc[i][j] = 0.f;
  #pragma unroll 4
  for (int kq = 0; kq < 32; ++kq) {
    float4 xv[4], wv[4];
    #pragma unroll
    for (int i = 0; i < 4; ++i) xv[i] = *(const float4*)&xl[(r4 + i) * 132 + kq * 4];
    #pragma unroll
    for (int j = 0; j < 4; ++j) wv[j] = *(const float4*)&wl[(c0 + 16 * j) * 132 + kq * 4];
    #pragma unroll
    for (int i = 0; i < 4; ++i)
      #pragma unroll
      for (int j = 0; j < 4; ++j) {
        acc[i][j] = fmaf(xv[i].x, wv[j].x, acc[i][j]);
        acc[i][j] = fmaf(xv[i].y, wv[j].y, acc[i][j]);
        acc[i][j] = fmaf(xv[i].z, wv[j].z, acc[i][j]);
        acc[i][j] = fmaf(xv[i].w, wv[j].w, acc[i][j]);
      }
  }
  #pragma unroll
  for (int i = 0; i < 4; ++i) {
    int r = row0 + r4 + i;
    if (r < N_NODES) {
      #pragma unroll
      for (int j = 0; j < 4; ++j) xw1[(size_t)r * 64 + c0 + 16 * j] = acc[i][j];
    }
  }
  float ps[4][4], pd[4][4];
  #pragma unroll
  for (int j = 0; j < 4; ++j) {
    float asv = as1[c0 + 16 * j], adv = ad1[c0 + 16 * j];
    #pragma unroll
    for (int i = 0; i < 4; ++i) { ps[i][j] = acc[i][j] * asv; pd[i][j] = acc[i][j] * adv; }
  }
  #pragma unroll
  for (int m = 1; m <= 4; m <<= 1)
    #pragma unroll
    for (int i = 0; i < 4; ++i)
      #pragma unroll
      for (int j = 0; j < 4; ++j) {
        ps[i][j] += __shfl_xor(ps[i][j], m);
        pd[i][j] += __shfl_xor(pd[i][j], m);
      }
  if ((t & 7) == 0) {
    int half = (c0 >> 3) & 1;
    #pragma unroll
    for (int i = 0; i < 4; ++i) {
      int r = row0 + r4 + i;
      if (r < N_NODES) {
        #pragma unroll
        for (int j = 0; j < 4; ++j) {
          int h = 2 * j + half;
          al_s1[r * 8 + h] = ps[i][j];
          al_d1[r * 8 + h] = pd[i][j];
        }
      }
    }
  }
}

// ---------------------------------------------------------------- layer-1 aggregate (online softmax, unroll-2), wave/node
__global__ void agg1_kernel(const int* __restrict__ offs, const int2* __restrict__ csr,
                            const float* __restrict__ ale1,
                            const float* __restrict__ al_s1, const float* __restrict__ al_d1,
                            const float* __restrict__ xw1,
                            const float* __restrict__ b1, float* __restrict__ h1) {
  int node = blockIdx.x * 4 + (threadIdx.x >> 6);
  if (node >= N_NODES) return;
  int lane = threadIdx.x & 63;
  int h = lane >> 3;
  int base = offs[node], end = offs[node + 1];
  int degn = end - base;
  float adv = al_d1[node * 8 + h];
  float m = -INFINITY, ssum = 0.f, acc = 0.f, sume = 0.f;
  int j = base;
  for (; j + 1 < end; j += 2) {
    int2 c0v = csr[j], c1v = csr[j + 1];
    float ae0 = ale1[(size_t)c0v.y * 8 + h];
    float ae1 = ale1[(size_t)c1v.y * 8 + h];
    float x0 = xw1[(size_t)c0v.x * 64 + lane];
    float x1 = xw1[(size_t)c1v.x * 64 + lane];
    float a0 = al_s1[c0v.x * 8 + h] + adv + ae0;
    float a1 = al_s1[c1v.x * 8 + h] + adv + ae1;
    sume += ae0 + ae1;
    a0 = (a0 > 0.f) ? a0 : 0.2f * a0;
    a1 = (a1 > 0.f) ? a1 : 0.2f * a1;
    float nm = fmaxf(m, fmaxf(a0, a1));
    float sc = __expf(m - nm), e0 = __expf(a0 - nm), e1 = __expf(a1 - nm);
    ssum = ssum * sc + e0 + e1;
    acc = acc * sc + e0 * x0 + e1 * x1;
    m = nm;
  }
  if (j < end) {
    int2 c0v = csr[j];
    float ae0 = ale1[(size_t)c0v.y * 8 + h];
    float x0 = xw1[(size_t)c0v.x * 64 + lane];
    float a0 = al_s1[c0v.x * 8 + h] + adv + ae0;
    sume += ae0;
    a0 = (a0 > 0.f) ? a0 : 0.2f * a0;
    float nm = fmaxf(m, a0);
    float sc = __expf(m - nm), e0 = __expf(a0 - nm);
    ssum = ssum * sc + e0;
    acc = acc * sc + e0 * x0;
    m = nm;
  }
  // self loop: al_e_self = mean of incoming al_e (linearity of ea @ M1)
  float aes = sume / (float)max(degn, 1);
  float a = al_s1[node * 8 + h] + adv + aes;
  a = (a > 0.f) ? a : 0.2f * a;
  float nm = fmaxf(m, a);
  float sc = __expf(m - nm);
  float e = __expf(a - nm);
  ssum = ssum * sc + e;
  acc = acc * sc + e * xw1[(size_t)node * 64 + lane];
  float o = acc / (ssum + 1e-16f) + b1[lane];
  h1[(size_t)node * 64 + lane] = (o > 0.f) ? o : expm1f(o);
}

// ---------------------------------------------------------------- gemm2: xw2 = h1 @ W2 (tiled), fused al_s2/al_d2
__global__ __launch_bounds__(256) void gemm2_kernel(
    const float* __restrict__ h1, const float* __restrict__ W2t,
    const float* __restrict__ as2, const float* __restrict__ ad2,
    float* __restrict__ xw2, float* __restrict__ al_s2, float* __restrict__ al_d2) {
  __shared__ float hl[64 * 68];    // 64 rows x (64 + 4 pad)
  __shared__ float wl[128 * 68];   // 128 cols x (64 + 4 pad)
  int t = threadIdx.x;
  int row0 = blockIdx.x * 64;
  const float4* hg = (const float4*)(h1 + (size_t)row0 * 64);
  const float4* wg = (const float4*)W2t;
  #pragma unroll
  for (int j = 0; j < 4; ++j) {   // 1024 float4s of h-tile
    int idx = t + j * 256;
    int r = idx >> 4, kq = idx & 15;
    float4 v = make_float4(0.f, 0.f, 0.f, 0.f);
    if (row0 + r < N_NODES) v = hg[r * 16 + kq];
    *(float4*)&hl[r * 68 + kq * 4] = v;
  }
  #pragma unroll
  for (int j = 0; j < 8; ++j) {   // 2048 float4s of W2t
    int idx = t + j * 256;
    int c = idx >> 4, kq = idx & 15;
    *(float4*)&wl[c * 68 + kq * 4] = wg[idx];
  }
  __syncthreads();
  int c0 = t & 31;
  int r8 = (t >> 5) * 8;
  float acc[8][4];
  #pragma unroll
  for (int i = 0; i < 8; ++i)
    #pragma unroll
    for (int j = 0; j < 4; ++j) acc[i][j] = 0.f;
  #pragma unroll 2
  for (int kq = 0; kq < 16; ++kq) {
    float4 xv[8], wv[4];
    #pragma unroll
    for (int i = 0; i < 8; ++i) xv[i] = *(const float4*)&hl[(r8 + i) * 68 + kq * 4];
    #pragma unroll
    for (int j = 0; j < 4; ++j) wv[j] = *(const float4*)&wl[(c0 + 32 * j) * 68 + kq * 4];
    #pragma unroll
    for (int i = 0; i < 8; ++i)
      #pragma unroll
      for (int j = 0; j < 4; ++j) {
        acc[i][j] = fmaf(xv[i].x, wv[j].x, acc[i][j]);
        acc[i][j] = fmaf(xv[i].y, wv[j].y, acc[i][j]);
        acc[i][j] = fmaf(xv[i].z, wv[j].z, acc[i][j]);
        acc[i][j] = fmaf(xv[i].w, wv[j].w, acc[i][j]);
      }
  }
  #pragma unroll
  for (int i = 0; i < 8; ++i) {
    int r = row0 + r8 + i;
    if (r < N_NODES) {
      #pragma unroll
      for (int j = 0; j < 4; ++j) xw2[(size_t)r * 128 + c0 + 32 * j] = acc[i][j];
    }
  }
  float ps[8], pd[8];
  #pragma unroll
  for (int i = 0; i < 8; ++i) { ps[i] = 0.f; pd[i] = 0.f; }
  #pragma unroll
  for (int j = 0; j < 4; ++j) {
    float asv = as2[c0 + 32 * j], adv = ad2[c0 + 32 * j];
    #pragma unroll
    for (int i = 0; i < 8; ++i) { ps[i] = fmaf(acc[i][j], asv, ps[i]); pd[i] = fmaf(acc[i][j], adv, pd[i]); }
  }
  #pragma unroll
  for (int m = 1; m <= 16; m <<= 1)
    #pragma unroll
    for (int i = 0; i < 8; ++i) {
      ps[i] += __shfl_xor(ps[i], m);
      pd[i] += __shfl_xor(pd[i], m);
    }
  if (c0 == 0) {
    #pragma unroll
    for (int i = 0; i < 8; ++i) {
      int r = row0 + r8 + i;
      if (r < N_NODES) { al_s2[r] = ps[i]; al_d2[r] = pd[i]; }
    }
  }
}

// ---------------------------------------------------------------- layer-2 aggregate (online softmax, unroll-2), wave/node
__global__ void agg2_kernel(const int* __restrict__ offs, const int2* __restrict__ csr,
                            const float* __restrict__ ale2,
                            const float* __restrict__ al_s2, const float* __restrict__ al_d2,
                            const float* __restrict__ xw2,
                            const float* __restrict__ b2, float* __restrict__ h2) {
  int node = blockIdx.x * 4 + (threadIdx.x >> 6);
  if (node >= N_NODES) return;
  int lane = threadIdx.x & 63;
  int base = offs[node], end = offs[node + 1];
  int degn = end - base;
  float adv = al_d2[node];
  float m = -INFINITY, ssum = 0.f, acc0 = 0.f, acc1 = 0.f, sume = 0.f;
  int j = base;
  for (; j + 1 < end; j += 2) {
    int2 c0v = csr[j], c1v = csr[j + 1];
    float ae0 = ale2[c0v.y];
    float ae1 = ale2[c1v.y];
    float x0a = xw2[(size_t)c0v.x * 128 + lane];
    float x0b = xw2[(size_t)c0v.x * 128 + 64 + lane];
    float x1a = xw2[(size_t)c1v.x * 128 + lane];
    float x1b = xw2[(size_t)c1v.x * 128 + 64 + lane];
    float a0 = al_s2[c0v.x] + adv + ae0;
    float a1 = al_s2[c1v.x] + adv + ae1;
    sume += ae0 + ae1;
    a0 = (a0 > 0.f) ? a0 : 0.2f * a0;
    a1 = (a1 > 0.f) ? a1 : 0.2f * a1;
    float nm = fmaxf(m, fmaxf(a0, a1));
    float sc = __expf(m - nm), e0 = __expf(a0 - nm), e1 = __expf(a1 - nm);
    ssum = ssum * sc + e0 + e1;
    acc0 = acc0 * sc + e0 * x0a + e1 * x1a;
    acc1 = acc1 * sc + e0 * x0b + e1 * x1b;
    m = nm;
  }
  if (j < end) {
    int2 c0v = csr[j];
    float ae0 = ale2[c0v.y];
    float x0a = xw2[(size_t)c0v.x * 128 + lane];
    float x0b = xw2[(size_t)c0v.x * 128 + 64 + lane];
    float a0 = al_s2[c0v.x] + adv + ae0;
    sume += ae0;
    a0 = (a0 > 0.f) ? a0 : 0.2f * a0;
    float nm = fmaxf(m, a0);
    float sc = __expf(m - nm), e0 = __expf(a0 - nm);
    ssum = ssum * sc + e0;
    acc0 = acc0 * sc + e0 * x0a;
    acc1 = acc1 * sc + e0 * x0b;
    m = nm;
  }
  float aes = sume / (float)max(degn, 1);
  float a = al_s2[node] + adv + aes;
  a = (a > 0.f) ? a : 0.2f * a;
  float nm = fmaxf(m, a);
  float sc = __expf(m - nm);
  float e = __expf(a - nm);
  ssum = ssum * sc + e;
  acc0 = acc0 * sc + e * xw2[(size_t)node * 128 + lane];
  acc1 = acc1 * sc + e * xw2[(size_t)node * 128 + 64 + lane];
  float inv = 1.f / (ssum + 1e-16f);
  h2[(size_t)node * 128 + lane] = acc0 * inv + b2[lane];
  h2[(size_t)node * 128 + 64 + lane] = acc1 * inv + b2[lane + 64];
}

// ---------------------------------------------------------------- graph boundaries (batch is sorted)
__global__ void gstart_kernel(const int* __restrict__ batch, int* __restrict__ gstart) {
  int n = blockIdx.x * blockDim.x + threadIdx.x;
  if (n >= N_NODES) return;
  int b = batch[n];
  if (n == 0) {
    for (int g = 0; g <= b; ++g) gstart[g] = 0;
  } else {
    int pb = batch[n - 1];
    for (int g = pb + 1; g <= b; ++g) gstart[g] = n;
  }
  if (n == N_NODES - 1) {
    for (int g = b + 1; g <= NGRAPH; ++g) gstart[g] = N_NODES;
  }
}

// ---------------------------------------------------------------- mean pool, block per graph
__global__ void pool_kernel(const float* __restrict__ h2, const int* __restrict__ gstart,
                            float* __restrict__ out) {
  int g = blockIdx.x;
  int c = threadIdx.x;  // 128
  int s0 = gstart[g], s1 = gstart[g + 1];
  float s = 0.f;
  for (int r = s0; r < s1; ++r) s += h2[(size_t)r * 128 + c];
  out[g * 128 + c] = s / fmaxf((float)(s1 - s0), 1.f);
}

// ================================================================ launch
extern "C" void kernel_launch(void* const* d_in, const int* in_sizes, int n_in,
                              void* d_out, int out_size, void* d_ws, size_t ws_size,
                              hipStream_t stream) {
  const float* x      = (const float*)d_in[0];
  const int*   eidx   = (const int*)d_in[1];
  const float* ea     = (const float*)d_in[2];
  const int*   batch  = (const int*)d_in[3];
  const float* W1     = (const float*)d_in[4];
  const float* as1    = (const float*)d_in[5];
  const float* ad1    = (const float*)d_in[6];
  const float* ae1    = (const float*)d_in[7];
  const float* We1    = (const float*)d_in[8];
  const float* b1     = (const float*)d_in[9];
  const float* W2     = (const float*)d_in[10];
  const float* as2    = (const float*)d_in[11];
  const float* ad2    = (const float*)d_in[12];
  const float* ae2    = (const float*)d_in[13];
  const float* We2    = (const float*)d_in[14];
  const float* b2     = (const float*)d_in[15];
  float* out = (float*)d_out;

  const int* src = eidx;
  const int* dst = eidx + N_EDGES;

  char* base = (char*)d_ws;
  size_t o = 0;
  #define ALLOC(name, bytes) size_t name = o; o += (((size_t)(bytes)) + 255) & ~(size_t)255;
  ALLOC(o_degcnt, 2 * N_NODES * 4)            // deg at [0,N), cnt at [N,2N)
  ALLOC(o_offs,   (N_NODES + 1) * 4)
  ALLOC(o_bsum,   256 * 4)
  ALLOC(o_csr,    (size_t)N_EDGES * 8)        // int2 {src, eid}
  ALLOC(o_ale1,   (size_t)N_EDGES * 8 * 4)    // edge-order, 32B/edge
  ALLOC(o_ale2,   (size_t)N_EDGES * 4)
  ALLOC(o_w1t,    64 * 128 * 4)
  ALLOC(o_w2t,    128 * 64 * 4)
  ALLOC(o_xw1,    (size_t)N_NODES * 64 * 4)   // also reused as h2 later
  ALLOC(o_als1,   N_NODES * 8 * 4)
  ALLOC(o_ald1,   N_NODES * 8 * 4)
  ALLOC(o_h1,     (size_t)N_NODES * 64 * 4)
  ALLOC(o_xw2,    (size_t)N_NODES * 128 * 4)
  ALLOC(o_als2,   N_NODES * 4)
  ALLOC(o_ald2,   N_NODES * 4)
  ALLOC(o_gs,     (NGRAPH + 1) * 4)
  #undef ALLOC

  int*   deg     = (int*)(base + o_degcnt);
  int*   cnt     = deg + N_NODES;
  int*   offs    = (int*)(base + o_offs);
  int*   bsum    = (int*)(base + o_bsum);
  int2*  csr     = (int2*)(base + o_csr);
  float* ale1    = (float*)(base + o_ale1);
  float* ale2    = (float*)(base + o_ale2);
  float* W1t     = (float*)(base + o_w1t);
  float* W2t     = (float*)(base + o_w2t);
  float* xw1     = (float*)(base + o_xw1);
  float* al_s1   = (float*)(base + o_als1);
  float* al_d1   = (float*)(base + o_ald1);
  float* h1      = (float*)(base + o_h1);
  float* xw2     = (float*)(base + o_xw2);
  float* al_s2   = (float*)(base + o_als2);
  float* al_d2   = (float*)(base + o_ald2);
  float* h2      = (float*)(base + o_xw1);   // alias: xw1+h1 dead after gemm2
  int*   gstart  = (int*)(base + o_gs);

  hipMemsetAsync(deg, 0, (size_t)2 * N_NODES * 4, stream);

  prep_kernel<<<32, 256, 0, stream>>>(W1, W2, W1t, W2t);
  histcalc_kernel<<<1024, 256, 0, stream>>>(dst, ea, We1, ae1, We2, ae2, deg, ale1, ale2);
  scan1_kernel<<<196, 256, 0, stream>>>(deg, offs, bsum);
  scan2_kernel<<<1, 256, 0, stream>>>(bsum);
  scan3_kernel<<<196, 256, 0, stream>>>(bsum, offs);
  scatter_kernel<<<1024, 256, 0, stream>>>(src, dst, offs, cnt, csr);
  gemm1_kernel<<<(N_NODES + 63) / 64, 256, 0, stream>>>(x, W1t, as1, ad1, xw1, al_s1, al_d1);
  agg1_kernel<<<(N_NODES + 3) / 4, 256, 0, stream>>>(offs, csr, ale1, al_s1, al_d1, xw1, b1, h1);
  gemm2_kernel<<<(N_NODES + 63) / 64, 256, 0, stream>>>(h1, W2t, as2, ad2, xw2, al_s2, al_d2);
  agg2_kernel<<<(N_NODES + 3) / 4, 256, 0, stream>>>(offs, csr, ale2, al_s2, al_d2, xw2, b2, h2);
  gstart_kernel<<<(N_NODES + 255) / 256, 256, 0, stream>>>(batch, gstart);
  pool_kernel<<<NGRAPH, 128, 0, stream>>>(h2, gstart, out);
}

// Round 10
// 479.043 us; speedup vs baseline: 1.9023x; 1.0169x over previous
//
#include <hip/hip_runtime.h>
#include <hip/hip_bf16.h>
#include <math.h>

#define N_NODES 50000
#define N_EDGES 800000
#define F_IN    128
#define ED_DIM  16
#define D1      64    /* H1*C1 */
#define NGRAPH  256
#define OUT_C   128

// ---------------------------------------------------------------- prep: transpose W1->W1t[64][128], W2->W2t[128][64]
__global__ void prep_kernel(const float* __restrict__ W1, const float* __restrict__ W2,
                            float* __restrict__ W1t, float* __restrict__ W2t) {
  int t = blockIdx.x * 256 + threadIdx.x;
  if (t < 64 * 128) {
    int k = t >> 6, c = t & 63;          // W1[k*64+c], k<128
    W1t[c * 128 + k] = W1[t];
    int k2 = t >> 7, c2 = t & 127;       // W2[k*128+c], k<64
    W2t[c2 * 64 + k2] = W2[t];
  }
}

// ---------------------------------------------------------------- fused histogram + edge-order attention logits
__global__ void histcalc_kernel(const int* __restrict__ dst, const float* __restrict__ ea,
                                const float* __restrict__ We1, const float* __restrict__ ae1w,
                                const float* __restrict__ We2, const float* __restrict__ ae2w,
                                int* __restrict__ deg,
                                float* __restrict__ ale1, float* __restrict__ ale2) {
  __shared__ float M1s[16][8];
  __shared__ float M2s[16];
  int t = threadIdx.x;
  if (t < 128) {
    int d = t >> 3, h = t & 7;
    float s = 0.f;
    #pragma unroll
    for (int c = 0; c < 8; ++c) s = fmaf(We1[d * 64 + h * 8 + c], ae1w[h * 8 + c], s);
    M1s[d][h] = s;
  } else if (t < 144) {
    int d = t - 128;
    float s = 0.f;
    for (int c = 0; c < 128; ++c) s = fmaf(We2[d * 128 + c], ae2w[c], s);
    M2s[d] = s;
  }
  __syncthreads();
  int i = blockIdx.x * blockDim.x + t;
  int stride = gridDim.x * blockDim.x;
  for (; i < N_EDGES; i += stride) {
    atomicAdd(&deg[dst[i]], 1);
    float e[16];
    const float4* ea4 = (const float4*)(ea + (size_t)i * 16);
    #pragma unroll
    for (int q = 0; q < 4; ++q) {
      float4 v = ea4[q];
      e[q * 4] = v.x; e[q * 4 + 1] = v.y; e[q * 4 + 2] = v.z; e[q * 4 + 3] = v.w;
    }
    float r[8];
    #pragma unroll
    for (int h = 0; h < 8; ++h) {
      float sacc = 0.f;
      #pragma unroll
      for (int dd = 0; dd < 16; ++dd) sacc = fmaf(e[dd], M1s[dd][h], sacc);
      r[h] = sacc;
    }
    float s2 = 0.f;
    #pragma unroll
    for (int dd = 0; dd < 16; ++dd) s2 = fmaf(e[dd], M2s[dd], s2);
    float4* o4 = (float4*)(ale1 + (size_t)i * 8);
    o4[0] = make_float4(r[0], r[1], r[2], r[3]);
    o4[1] = make_float4(r[4], r[5], r[6], r[7]);
    ale2[i] = s2;
  }
}

// ---------------------------------------------------------------- hierarchical scan (3 kernels)
__global__ void scan1_kernel(const int* __restrict__ deg, int* __restrict__ offs,
                             int* __restrict__ bsum) {
  __shared__ int sh[256];
  int b = blockIdx.x, t = threadIdx.x, i = b * 256 + t;
  int v = (i < N_NODES) ? deg[i] : 0;
  sh[t] = v;
  __syncthreads();
  for (int o = 1; o < 256; o <<= 1) {
    int tv = (t >= o) ? sh[t - o] : 0;
    __syncthreads();
    sh[t] += tv;
    __syncthreads();
  }
  if (i < N_NODES) offs[i + 1] = sh[t];
  if (t == 255) bsum[b] = sh[255];
}

__global__ void scan2_kernel(int* __restrict__ bsum) {  // 196 entries, 1 block
  __shared__ int sh[256];
  int t = threadIdx.x;
  sh[t] = (t < 196) ? bsum[t] : 0;
  __syncthreads();
  for (int o = 1; o < 256; o <<= 1) {
    int tv = (t >= o) ? sh[t - o] : 0;
    __syncthreads();
    sh[t] += tv;
    __syncthreads();
  }
  if (t < 196) bsum[t] = (t > 0) ? sh[t - 1] : 0;  // exclusive
}

__global__ void scan3_kernel(const int* __restrict__ bsum, int* __restrict__ offs) {
  int b = blockIdx.x, t = threadIdx.x, i = b * 256 + t;
  if (i < N_NODES) offs[i + 1] += bsum[b];
  if (i == 0) offs[0] = 0;
}

// ---------------------------------------------------------------- scatter indices only: csr[pos] = {src, eid} (8B)
__global__ void scatter_kernel(const int* __restrict__ src, const int* __restrict__ dst,
                               const int* __restrict__ offs, int* __restrict__ cnt,
                               int2* __restrict__ csr) {
  int i = blockIdx.x * blockDim.x + threadIdx.x;
  int stride = gridDim.x * blockDim.x;
  for (; i < N_EDGES; i += stride) {
    int d = dst[i];
    int pos = offs[d] + atomicAdd(&cnt[d], 1);
    csr[pos] = make_int2(src[i], i);
  }
}

// ---------------------------------------------------------------- gemm1: xw1 = x @ W1 (tiled), fused al_s1/al_d1
__global__ __launch_bounds__(256) void gemm1_kernel(
    const float* __restrict__ x, const float* __restrict__ W1t,
    const float* __restrict__ as1, const float* __restrict__ ad1,
    float* __restrict__ xw1, float* __restrict__ al_s1, float* __restrict__ al_d1) {
  __shared__ float xl[64 * 132];   // 64 rows x (128 + 4 pad)
  __shared__ float wl[64 * 132];   // 64 cols x (128 + 4 pad)
  int t = threadIdx.x;
  int row0 = blockIdx.x * 64;
  const float4* xg = (const float4*)(x + (size_t)row0 * 128);
  const float4* wg = (const float4*)W1t;
  #pragma unroll
  for (int j = 0; j < 8; ++j) {
    int idx = t + j * 256;          // float4 index in 64x32 grid
    int r = idx >> 5, kq = idx & 31;
    float4 v = make_float4(0.f, 0.f, 0.f, 0.f);
    if (row0 + r < N_NODES) v = xg[r * 32 + kq];
    *(float4*)&xl[r * 132 + kq * 4] = v;
    *(float4*)&wl[(idx >> 5) * 132 + kq * 4] = wg[idx];
  }
  __syncthreads();
  int c0 = t & 15;
  int r4 = (t >> 4) * 4;
  float acc[4][4];
  #pragma unroll
  for (int i = 0; i < 4; ++i)
    #pragma unroll
    for (int j = 0; j < 4; ++j) acc[i][j] = 0.f;
  #pragma unroll 4
  for (int kq = 0; kq < 32; ++kq) {
    float4 xv[4], wv[4];
    #pragma unroll
    for (int i = 0; i < 4; ++i) xv[i] = *(const float4*)&xl[(r4 + i) * 132 + kq * 4];
    #pragma unroll
    for (int j = 0; j < 4; ++j) wv[j] = *(const float4*)&wl[(c0 + 16 * j) * 132 + kq * 4];
    #pragma unroll
    for (int i = 0; i < 4; ++i)
      #pragma unroll
      for (int j = 0; j < 4; ++j) {
        acc[i][j] = fmaf(xv[i].x, wv[j].x, acc[i][j]);
        acc[i][j] = fmaf(xv[i].y, wv[j].y, acc[i][j]);
        acc[i][j] = fmaf(xv[i].z, wv[j].z, acc[i][j]);
        acc[i][j] = fmaf(xv[i].w, wv[j].w, acc[i][j]);
      }
  }
  #pragma unroll
  for (int i = 0; i < 4; ++i) {
    int r = row0 + r4 + i;
    if (r < N_NODES) {
      #pragma unroll
      for (int j = 0; j < 4; ++j) xw1[(size_t)r * 64 + c0 + 16 * j] = acc[i][j];
    }
  }
  float ps[4][4], pd[4][4];
  #pragma unroll
  for (int j = 0; j < 4; ++j) {
    float asv = as1[c0 + 16 * j], adv = ad1[c0 + 16 * j];
    #pragma unroll
    for (int i = 0; i < 4; ++i) { ps[i][j] = acc[i][j] * asv; pd[i][j] = acc[i][j] * adv; }
  }
  #pragma unroll
  for (int m = 1; m <= 4; m <<= 1)
    #pragma unroll
    for (int i = 0; i < 4; ++i)
      #pragma unroll
      for (int j = 0; j < 4; ++j) {
        ps[i][j] += __shfl_xor(ps[i][j], m);
        pd[i][j] += __shfl_xor(pd[i][j], m);
      }
  if ((t & 7) == 0) {
    int half = (c0 >> 3) & 1;
    #pragma unroll
    for (int i = 0; i < 4; ++i) {
      int r = row0 + r4 + i;
      if (r < N_NODES) {
        #pragma unroll
        for (int j = 0; j < 4; ++j) {
          int h = 2 * j + half;
          al_s1[r * 8 + h] = ps[i][j];
          al_d1[r * 8 + h] = pd[i][j];
        }
      }
    }
  }
}

// ---------------------------------------------------------------- layer-1 aggregate (no-rescale softmax, unroll-4)
__global__ void agg1_kernel(const int* __restrict__ offs, const int2* __restrict__ csr,
                            const float* __restrict__ ale1,
                            const float* __restrict__ al_s1, const float* __restrict__ al_d1,
                            const float* __restrict__ xw1,
                            const float* __restrict__ b1, float* __restrict__ h1) {
  int node = blockIdx.x * 4 + (threadIdx.x >> 6);
  if (node >= N_NODES) return;
  int lane = threadIdx.x & 63;
  int h = lane >> 3;
  int base = offs[node], end = offs[node + 1];
  int degn = end - base;
  float adv = al_d1[node * 8 + h];
  float ssum = 0.f, acc = 0.f, sume = 0.f;
  int j = base;
  for (; j + 3 < end; j += 4) {
    int2 c0v = csr[j], c1v = csr[j + 1], c2v = csr[j + 2], c3v = csr[j + 3];
    float ae0 = ale1[(size_t)c0v.y * 8 + h];
    float ae1 = ale1[(size_t)c1v.y * 8 + h];
    float ae2 = ale1[(size_t)c2v.y * 8 + h];
    float ae3 = ale1[(size_t)c3v.y * 8 + h];
    float x0 = xw1[(size_t)c0v.x * 64 + lane];
    float x1 = xw1[(size_t)c1v.x * 64 + lane];
    float x2 = xw1[(size_t)c2v.x * 64 + lane];
    float x3 = xw1[(size_t)c3v.x * 64 + lane];
    float a0 = al_s1[c0v.x * 8 + h] + adv + ae0;
    float a1 = al_s1[c1v.x * 8 + h] + adv + ae1;
    float a2 = al_s1[c2v.x * 8 + h] + adv + ae2;
    float a3 = al_s1[c3v.x * 8 + h] + adv + ae3;
    sume += (ae0 + ae1) + (ae2 + ae3);
    a0 = (a0 > 0.f) ? a0 : 0.2f * a0;
    a1 = (a1 > 0.f) ? a1 : 0.2f * a1;
    a2 = (a2 > 0.f) ? a2 : 0.2f * a2;
    a3 = (a3 > 0.f) ? a3 : 0.2f * a3;
    float e0 = __expf(a0), e1 = __expf(a1), e2 = __expf(a2), e3 = __expf(a3);
    ssum += (e0 + e1) + (e2 + e3);
    acc = fmaf(e0, x0, acc); acc = fmaf(e1, x1, acc);
    acc = fmaf(e2, x2, acc); acc = fmaf(e3, x3, acc);
  }
  for (; j < end; ++j) {
    int2 c0v = csr[j];
    float ae0 = ale1[(size_t)c0v.y * 8 + h];
    float x0 = xw1[(size_t)c0v.x * 64 + lane];
    float a0 = al_s1[c0v.x * 8 + h] + adv + ae0;
    sume += ae0;
    a0 = (a0 > 0.f) ? a0 : 0.2f * a0;
    float e0 = __expf(a0);
    ssum += e0;
    acc = fmaf(e0, x0, acc);
  }
  // self loop: al_e_self = mean of incoming al_e (linearity of ea @ M1)
  float aes = sume / (float)max(degn, 1);
  float a = al_s1[node * 8 + h] + adv + aes;
  a = (a > 0.f) ? a : 0.2f * a;
  float e = __expf(a);
  ssum += e;
  acc = fmaf(e, xw1[(size_t)node * 64 + lane], acc);
  float o = acc / (ssum + 1e-16f) + b1[lane];
  h1[(size_t)node * 64 + lane] = (o > 0.f) ? o : expm1f(o);
}

// ---------------------------------------------------------------- gemm2: xw2 = h1 @ W2 (tiled), fused al_s2/al_d2
__global__ __launch_bounds__(256) void gemm2_kernel(
    const float* __restrict__ h1, const float* __restrict__ W2t,
    const float* __restrict__ as2, const float* __restrict__ ad2,
    float* __restrict__ xw2, float* __restrict__ al_s2, float* __restrict__ al_d2) {
  __shared__ float hl[64 * 68];    // 64 rows x (64 + 4 pad)
  __shared__ float wl[128 * 68];   // 128 cols x (64 + 4 pad)
  int t = threadIdx.x;
  int row0 = blockIdx.x * 64;
  const float4* hg = (const float4*)(h1 + (size_t)row0 * 64);
  const float4* wg = (const float4*)W2t;
  #pragma unroll
  for (int j = 0; j < 4; ++j) {   // 1024 float4s of h-tile
    int idx = t + j * 256;
    int r = idx >> 4, kq = idx & 15;
    float4 v = make_float4(0.f, 0.f, 0.f, 0.f);
    if (row0 + r < N_NODES) v = hg[r * 16 + kq];
    *(float4*)&hl[r * 68 + kq * 4] = v;
  }
  #pragma unroll
  for (int j = 0; j < 8; ++j) {   // 2048 float4s of W2t
    int idx = t + j * 256;
    int c = idx >> 4, kq = idx & 15;
    *(float4*)&wl[c * 68 + kq * 4] = wg[idx];
  }
  __syncthreads();
  int c0 = t & 31;
  int r8 = (t >> 5) * 8;
  float acc[8][4];
  #pragma unroll
  for (int i = 0; i < 8; ++i)
    #pragma unroll
    for (int j = 0; j < 4; ++j) acc[i][j] = 0.f;
  #pragma unroll 2
  for (int kq = 0; kq < 16; ++kq) {
    float4 xv[8], wv[4];
    #pragma unroll
    for (int i = 0; i < 8; ++i) xv[i] = *(const float4*)&hl[(r8 + i) * 68 + kq * 4];
    #pragma unroll
    for (int j = 0; j < 4; ++j) wv[j] = *(const float4*)&wl[(c0 + 32 * j) * 68 + kq * 4];
    #pragma unroll
    for (int i = 0; i < 8; ++i)
      #pragma unroll
      for (int j = 0; j < 4; ++j) {
        acc[i][j] = fmaf(xv[i].x, wv[j].x, acc[i][j]);
        acc[i][j] = fmaf(xv[i].y, wv[j].y, acc[i][j]);
        acc[i][j] = fmaf(xv[i].z, wv[j].z, acc[i][j]);
        acc[i][j] = fmaf(xv[i].w, wv[j].w, acc[i][j]);
      }
  }
  #pragma unroll
  for (int i = 0; i < 8; ++i) {
    int r = row0 + r8 + i;
    if (r < N_NODES) {
      #pragma unroll
      for (int j = 0; j < 4; ++j) xw2[(size_t)r * 128 + c0 + 32 * j] = acc[i][j];
    }
  }
  float ps[8], pd[8];
  #pragma unroll
  for (int i = 0; i < 8; ++i) { ps[i] = 0.f; pd[i] = 0.f; }
  #pragma unroll
  for (int j = 0; j < 4; ++j) {
    float asv = as2[c0 + 32 * j], adv = ad2[c0 + 32 * j];
    #pragma unroll
    for (int i = 0; i < 8; ++i) { ps[i] = fmaf(acc[i][j], asv, ps[i]); pd[i] = fmaf(acc[i][j], adv, pd[i]); }
  }
  #pragma unroll
  for (int m = 1; m <= 16; m <<= 1)
    #pragma unroll
    for (int i = 0; i < 8; ++i) {
      ps[i] += __shfl_xor(ps[i], m);
      pd[i] += __shfl_xor(pd[i], m);
    }
  if (c0 == 0) {
    #pragma unroll
    for (int i = 0; i < 8; ++i) {
      int r = row0 + r8 + i;
      if (r < N_NODES) { al_s2[r] = ps[i]; al_d2[r] = pd[i]; }
    }
  }
}

// ---------------------------------------------------------------- layer-2 aggregate (no-rescale softmax, unroll-4)
__global__ void agg2_kernel(const int* __restrict__ offs, const int2* __restrict__ csr,
                            const float* __restrict__ ale2,
                            const float* __restrict__ al_s2, const float* __restrict__ al_d2,
                            const float* __restrict__ xw2,
                            const float* __restrict__ b2, float* __restrict__ h2) {
  int node = blockIdx.x * 4 + (threadIdx.x >> 6);
  if (node >= N_NODES) return;
  int lane = threadIdx.x & 63;
  int base = offs[node], end = offs[node + 1];
  int degn = end - base;
  float adv = al_d2[node];
  float ssum = 0.f, acc0 = 0.f, acc1 = 0.f, sume = 0.f;
  int j = base;
  for (; j + 3 < end; j += 4) {
    int2 c0v = csr[j], c1v = csr[j + 1], c2v = csr[j + 2], c3v = csr[j + 3];
    float ae0 = ale2[c0v.y], ae1 = ale2[c1v.y], ae2 = ale2[c2v.y], ae3 = ale2[c3v.y];
    float x0a = xw2[(size_t)c0v.x * 128 + lane];
    float x0b = xw2[(size_t)c0v.x * 128 + 64 + lane];
    float x1a = xw2[(size_t)c1v.x * 128 + lane];
    float x1b = xw2[(size_t)c1v.x * 128 + 64 + lane];
    float x2a = xw2[(size_t)c2v.x * 128 + lane];
    float x2b = xw2[(size_t)c2v.x * 128 + 64 + lane];
    float x3a = xw2[(size_t)c3v.x * 128 + lane];
    float x3b = xw2[(size_t)c3v.x * 128 + 64 + lane];
    float a0 = al_s2[c0v.x] + adv + ae0;
    float a1 = al_s2[c1v.x] + adv + ae1;
    float a2 = al_s2[c2v.x] + adv + ae2;
    float a3 = al_s2[c3v.x] + adv + ae3;
    sume += (ae0 + ae1) + (ae2 + ae3);
    a0 = (a0 > 0.f) ? a0 : 0.2f * a0;
    a1 = (a1 > 0.f) ? a1 : 0.2f * a1;
    a2 = (a2 > 0.f) ? a2 : 0.2f * a2;
    a3 = (a3 > 0.f) ? a3 : 0.2f * a3;
    float e0 = __expf(a0), e1 = __expf(a1), e2 = __expf(a2), e3 = __expf(a3);
    ssum += (e0 + e1) + (e2 + e3);
    acc0 = fmaf(e0, x0a, acc0); acc0 = fmaf(e1, x1a, acc0);
    acc0 = fmaf(e2, x2a, acc0); acc0 = fmaf(e3, x3a, acc0);
    acc1 = fmaf(e0, x0b, acc1); acc1 = fmaf(e1, x1b, acc1);
    acc1 = fmaf(e2, x2b, acc1); acc1 = fmaf(e3, x3b, acc1);
  }
  for (; j < end; ++j) {
    int2 c0v = csr[j];
    float ae0 = ale2[c0v.y];
    float x0a = xw2[(size_t)c0v.x * 128 + lane];
    float x0b = xw2[(size_t)c0v.x * 128 + 64 + lane];
    float a0 = al_s2[c0v.x] + adv + ae0;
    sume += ae0;
    a0 = (a0 > 0.f) ? a0 : 0.2f * a0;
    float e0 = __expf(a0);
    ssum += e0;
    acc0 = fmaf(e0, x0a, acc0);
    acc1 = fmaf(e0, x0b, acc1);
  }
  float aes = sume / (float)max(degn, 1);
  float a = al_s2[node] + adv + aes;
  a = (a > 0.f) ? a : 0.2f * a;
  float e = __expf(a);
  ssum += e;
  acc0 = fmaf(e, xw2[(size_t)node * 128 + lane], acc0);
  acc1 = fmaf(e, xw2[(size_t)node * 128 + 64 + lane], acc1);
  float inv = 1.f / (ssum + 1e-16f);
  h2[(size_t)node * 128 + lane] = acc0 * inv + b2[lane];
  h2[(size_t)node * 128 + 64 + lane] = acc1 * inv + b2[lane + 64];
}

// ---------------------------------------------------------------- graph boundaries (batch is sorted)
__global__ void gstart_kernel(const int* __restrict__ batch, int* __restrict__ gstart) {
  int n = blockIdx.x * blockDim.x + threadIdx.x;
  if (n >= N_NODES) return;
  int b = batch[n];
  if (n == 0) {
    for (int g = 0; g <= b; ++g) gstart[g] = 0;
  } else {
    int pb = batch[n - 1];
    for (int g = pb + 1; g <= b; ++g) gstart[g] = n;
  }
  if (n == N_NODES - 1) {
    for (int g = b + 1; g <= NGRAPH; ++g) gstart[g] = N_NODES;
  }
}

// ---------------------------------------------------------------- mean pool, block per graph
__global__ void pool_kernel(const float* __restrict__ h2, const int* __restrict__ gstart,
                            float* __restrict__ out) {
  int g = blockIdx.x;
  int c = threadIdx.x;  // 128
  int s0 = gstart[g], s1 = gstart[g + 1];
  float s = 0.f;
  for (int r = s0; r < s1; ++r) s += h2[(size_t)r * 128 + c];
  out[g * 128 + c] = s / fmaxf((float)(s1 - s0), 1.f);
}

// ================================================================ launch
extern "C" void kernel_launch(void* const* d_in, const int* in_sizes, int n_in,
                              void* d_out, int out_size, void* d_ws, size_t ws_size,
                              hipStream_t stream) {
  const float* x      = (const float*)d_in[0];
  const int*   eidx   = (const int*)d_in[1];
  const float* ea     = (const float*)d_in[2];
  const int*   batch  = (const int*)d_in[3];
  const float* W1     = (const float*)d_in[4];
  const float* as1    = (const float*)d_in[5];
  const float* ad1    = (const float*)d_in[6];
  const float* ae1    = (const float*)d_in[7];
  const float* We1    = (const float*)d_in[8];
  const float* b1     = (const float*)d_in[9];
  const float* W2     = (const float*)d_in[10];
  const float* as2    = (const float*)d_in[11];
  const float* ad2    = (const float*)d_in[12];
  const float* ae2    = (const float*)d_in[13];
  const float* We2    = (const float*)d_in[14];
  const float* b2     = (const float*)d_in[15];
  float* out = (float*)d_out;

  const int* src = eidx;
  const int* dst = eidx + N_EDGES;

  char* base = (char*)d_ws;
  size_t o = 0;
  #define ALLOC(name, bytes) size_t name = o; o += (((size_t)(bytes)) + 255) & ~(size_t)255;
  ALLOC(o_degcnt, 2 * N_NODES * 4)            // deg at [0,N), cnt at [N,2N)
  ALLOC(o_offs,   (N_NODES + 1) * 4)
  ALLOC(o_bsum,   256 * 4)
  ALLOC(o_csr,    (size_t)N_EDGES * 8)        // int2 {src, eid}
  ALLOC(o_ale1,   (size_t)N_EDGES * 8 * 4)    // edge-order, 32B/edge
  ALLOC(o_ale2,   (size_t)N_EDGES * 4)
  ALLOC(o_w1t,    64 * 128 * 4)
  ALLOC(o_w2t,    128 * 64 * 4)
  ALLOC(o_xw1,    (size_t)N_NODES * 64 * 4)   // also reused as h2 later
  ALLOC(o_als1,   N_NODES * 8 * 4)
  ALLOC(o_ald1,   N_NODES * 8 * 4)
  ALLOC(o_h1,     (size_t)N_NODES * 64 * 4)
  ALLOC(o_xw2,    (size_t)N_NODES * 128 * 4)
  ALLOC(o_als2,   N_NODES * 4)
  ALLOC(o_ald2,   N_NODES * 4)
  ALLOC(o_gs,     (NGRAPH + 1) * 4)
  #undef ALLOC

  int*   deg     = (int*)(base + o_degcnt);
  int*   cnt     = deg + N_NODES;
  int*   offs    = (int*)(base + o_offs);
  int*   bsum    = (int*)(base + o_bsum);
  int2*  csr     = (int2*)(base + o_csr);
  float* ale1    = (float*)(base + o_ale1);
  float* ale2    = (float*)(base + o_ale2);
  float* W1t     = (float*)(base + o_w1t);
  float* W2t     = (float*)(base + o_w2t);
  float* xw1     = (float*)(base + o_xw1);
  float* al_s1   = (float*)(base + o_als1);
  float* al_d1   = (float*)(base + o_ald1);
  float* h1      = (float*)(base + o_h1);
  float* xw2     = (float*)(base + o_xw2);
  float* al_s2   = (float*)(base + o_als2);
  float* al_d2   = (float*)(base + o_ald2);
  float* h2      = (float*)(base + o_xw1);   // alias: xw1+h1 dead after gemm2
  int*   gstart  = (int*)(base + o_gs);

  hipMemsetAsync(deg, 0, (size_t)2 * N_NODES * 4, stream);

  prep_kernel<<<32, 256, 0, stream>>>(W1, W2, W1t, W2t);
  histcalc_kernel<<<1024, 256, 0, stream>>>(dst, ea, We1, ae1, We2, ae2, deg, ale1, ale2);
  scan1_kernel<<<196, 256, 0, stream>>>(deg, offs, bsum);
  scan2_kernel<<<1, 256, 0, stream>>>(bsum);
  scan3_kernel<<<196, 256, 0, stream>>>(bsum, offs);
  scatter_kernel<<<1024, 256, 0, stream>>>(src, dst, offs, cnt, csr);
  gemm1_kernel<<<(N_NODES + 63) / 64, 256, 0, stream>>>(x, W1t, as1, ad1, xw1, al_s1, al_d1);
  agg1_kernel<<<(N_NODES + 3) / 4, 256, 0, stream>>>(offs, csr, ale1, al_s1, al_d1, xw1, b1, h1);
  gemm2_kernel<<<(N_NODES + 63) / 64, 256, 0, stream>>>(h1, W2t, as2, ad2, xw2, al_s2, al_d2);
  agg2_kernel<<<(N_NODES + 3) / 4, 256, 0, stream>>>(offs, csr, ale2, al_s2, al_d2, xw2, b2, h2);
  gstart_kernel<<<(N_NODES + 255) / 256, 256, 0, stream>>>(batch, gstart);
  pool_kernel<<<NGRAPH, 128, 0, stream>>>(h2, gstart, out);
}